// Round 11
// baseline (3083.339 us; speedup 1.0000x reference)
//
#include <hip/hip_runtime.h>
#include <stdint.h>
#include <math.h>

// ============================================================================
// POGLM.sample — bit-exact replication of the JAX-CPU reference.
// R11: z-phase conv broadcasts moved OFF the LDS pipe. R10 was LDS-pipe-bound:
//      64 ds_read_b128 broadcasts/wave/step x 4 waves x ~12cy = ~3070cy/step.
//      Now each lane reads 4 conv floats (conflict-free b32) and the wave
//      broadcasts them with v_readlane (VALU pipe) into the FMA chain.
//      Same operands, same ascending-k order -> bit-identical z.
//      Weights stay AGPR-resident (R7/R10 def+use class-locked pattern).
//      Poisson via precomputed S-prefix table (R9).
// Variant knobs:
#define THREEFRY_PARTITIONABLE 1
#define BITS32_XOR 1
#define VSL_FMA 0
#define CONV_FMA 0
#define RAW_BARRIER 1
#define POISSON_BATCH 4   // inline-path batch (MODE 0 fallback)
#define NT_STORES 1
#define J_PRE 8           // precomputed prefix depth
// ============================================================================

#define T_BINS 1024
#define N_SAMP 64
#define N_NEUR 256
#define J_MAX 32
#define LANES (N_SAMP * N_NEUR)  // 16384

// d_ws layout:
#define SUB_BYTES   (T_BINS * 2 * J_MAX * 4)
#define HIST_OFF    SUB_BYTES
#define HIST_BYTES  (20 * LANES * 4)
#define STBL_OFF    (HIST_OFF + HIST_BYTES)

// --- strict (non-contractable) f32 ops ---
static __device__ __forceinline__ float fmul_s(float a, float b) {
#pragma clang fp contract(off)
  return a * b;
}
static __device__ __forceinline__ float fadd_s(float a, float b) {
#pragma clang fp contract(off)
  return a + b;
}
static __device__ __forceinline__ float fsub_s(float a, float b) {
#pragma clang fp contract(off)
  return a - b;
}

#if VSL_FMA
#define MULADD(a, b, c) __builtin_fmaf((a), (b), (c))
#else
#define MULADD(a, b, c) fadd_s(fmul_s((a), (b)), (c))
#endif

// --- Threefry-2x32, 20 rounds (exact JAX semantics) ---
static __device__ __forceinline__ uint32_t rotl(uint32_t v, uint32_t d) {
  return (v << d) | (v >> (32u - d));
}
static __device__ __forceinline__ void threefry2x32(uint32_t k0, uint32_t k1,
                                                    uint32_t x0, uint32_t x1,
                                                    uint32_t& o0, uint32_t& o1) {
  const uint32_t k2 = k0 ^ k1 ^ 0x1BD11BDAu;
  x0 += k0; x1 += k1;
#define TF_RD(r) { x0 += x1; x1 = rotl(x1, r); x1 ^= x0; }
  TF_RD(13u) TF_RD(15u) TF_RD(26u) TF_RD(6u)
  x0 += k1; x1 += k2 + 1u;
  TF_RD(17u) TF_RD(29u) TF_RD(16u) TF_RD(24u)
  x0 += k2; x1 += k0 + 2u;
  TF_RD(13u) TF_RD(15u) TF_RD(26u) TF_RD(6u)
  x0 += k0; x1 += k1 + 3u;
  TF_RD(17u) TF_RD(29u) TF_RD(16u) TF_RD(24u)
  x0 += k1; x1 += k2 + 4u;
  TF_RD(13u) TF_RD(15u) TF_RD(26u) TF_RD(6u)
  x0 += k2; x1 += k0 + 5u;
#undef TF_RD
  o0 = x0; o1 = x1;
}

// --- XLA CPU Cephes expf (GenerateVF32Exp) ---
static __device__ __forceinline__ float xla_expf(float input) {
  float x = fminf(input, 88.3762626647950f);
  x = fmaxf(x, -88.3762626647949f);
  float fx = floorf(MULADD(x, 1.44269504088896341f, 0.5f));
  float tmp = fmul_s(0.693359375f, fx);
  float z = fmul_s(-2.12194440e-4f, fx);
  x = fsub_s(x, tmp);
  x = fsub_s(x, z);
  z = fmul_s(x, x);
  float y = MULADD(x, 1.9875691500e-4f, 1.3981999507e-3f);
  y = MULADD(y, x, 8.3334519073e-3f);
  y = MULADD(y, x, 4.1665795894e-2f);
  y = MULADD(y, x, 1.6666665459e-1f);
  y = MULADD(y, x, 5.0000001201e-1f);
  y = MULADD(y, z, x);
  y = fadd_s(1.0f, y);
  int n = (int)fx;
  float p2n = __int_as_float((uint32_t)(n + 127) << 23);
  float res = fmul_s(y, p2n);
  return fmaxf(res, input);
}

// --- XLA CPU Cephes logf (GenerateVF32Log); u in {0} U [2^-23, 1) here ---
static __device__ __forceinline__ float xla_logf(float u) {
  if (u == 0.0f) return -INFINITY;
  uint32_t b = __float_as_uint(u);
  float e = (float)((int)(b >> 23) - 127) + 1.0f;
  float m = __uint_as_float((b & 0x007fffffu) | 0x3f000000u);
  if (m < 0.707106781186547524f) {
    e = fsub_s(e, 1.0f);
    m = fadd_s(m, m);
  }
  m = fsub_s(m, 1.0f);
  float z = fmul_s(m, m);
  float y = MULADD(m, 7.0376836292e-2f, -1.1514610310e-1f);
  y = MULADD(y, m, 1.1676998740e-1f);
  y = MULADD(y, m, -1.2420140846e-1f);
  y = MULADD(y, m, 1.4249322787e-1f);
  y = MULADD(y, m, -1.6668057665e-1f);
  y = MULADD(y, m, 2.0000714765e-1f);
  y = MULADD(y, m, -2.4999993993e-1f);
  y = MULADD(y, m, 3.3333331174e-1f);
  y = fmul_s(y, m);
  y = fmul_s(y, z);
  y = MULADD(e, -2.12194440e-4f, y);
  y = MULADD(z, -0.5f, y);
  m = fadd_s(m, y);
  m = MULADD(e, 0.693359375f, m);
  return m;
}

// ============================================================================
// Kernel 1: per-time-step subkey chains. sub layout: [t][j][2] u32.
// ============================================================================
__global__ void poglm_subkeys(uint32_t* __restrict__ sub) {
  int t = blockIdx.x * blockDim.x + threadIdx.x;
  if (t >= T_BINS) return;
  uint32_t kt0, kt1;
#if THREEFRY_PARTITIONABLE
  threefry2x32(0u, 1u, 0u, (uint32_t)t, kt0, kt1);
#else
  {
    uint32_t i0 = 2u * t, i1 = 2u * t + 1u, a0, a1, b0, b1;
    if (i0 < 1024u) { threefry2x32(0u, 1u, i0, i0 + 1024u, a0, a1); kt0 = a0; }
    else            { threefry2x32(0u, 1u, i0 - 1024u, i0, a0, a1); kt0 = a1; }
    if (i1 < 1024u) { threefry2x32(0u, 1u, i1, i1 + 1024u, b0, b1); kt1 = b0; }
    else            { threefry2x32(0u, 1u, i1 - 1024u, i1, b0, b1); kt1 = b1; }
  }
#endif
  uint32_t r0 = kt0, r1 = kt1;
  for (int j = 0; j < J_MAX; ++j) {
    uint32_t s0, s1, n0, n1;
#if THREEFRY_PARTITIONABLE
    threefry2x32(r0, r1, 0u, 1u, s0, s1);
    threefry2x32(r0, r1, 0u, 0u, n0, n1);
#else
    uint32_t p00, p01, p10, p11;
    threefry2x32(r0, r1, 0u, 2u, p00, p01);
    threefry2x32(r0, r1, 1u, 3u, p10, p11);
    n0 = p00; n1 = p10;
    s0 = p01; s1 = p11;
#endif
    sub[(size_t)t * (2 * J_MAX) + 2 * j + 0] = s0;
    sub[(size_t)t * (2 * J_MAX) + 2 * j + 1] = s1;
    r0 = n0; r1 = n1;
  }
}

// ============================================================================
// Kernel 1b: S-prefix table (R9). S8[((t-t0)*LANES + idx)*8 + j].
// ============================================================================
__global__ __launch_bounds__(256)
void poglm_stable(const uint32_t* __restrict__ sub, float* __restrict__ S8,
                  int t0) {
  const int g   = blockIdx.x * 256 + threadIdx.x;
  const int tt  = t0 + g / LANES;
  const int ln  = g % LANES;
  float S = 0.0f;
  float v[J_PRE];
#pragma unroll
  for (int j = 0; j < J_PRE; ++j) {
    const uint32_t k0 = sub[(size_t)tt * (2 * J_MAX) + 2 * j];
    const uint32_t k1 = sub[(size_t)tt * (2 * J_MAX) + 2 * j + 1];
    uint32_t o0, o1;
    threefry2x32(k0, k1, 0u, (uint32_t)ln, o0, o1);
#if BITS32_XOR
    const uint32_t bits = o0 ^ o1;
#else
    const uint32_t bits = o1;
#endif
    const float u = __uint_as_float((bits >> 9) | 0x3f800000u) - 1.0f;
    S = fadd_s(S, xla_logf(u));
    v[j] = S;
  }
  float4* dst = reinterpret_cast<float4*>(S8 + (size_t)g * J_PRE);
  dst[0] = make_float4(v[0], v[1], v[2], v[3]);
  dst[1] = make_float4(v[4], v[5], v[6], v[7]);
}

// ---- 64 x float4 = 256 AGPR-resident weights --------------------------------
#define FOR64(M) \
  M(0) M(1) M(2) M(3) M(4) M(5) M(6) M(7) M(8) M(9) M(10) M(11) M(12) M(13) \
  M(14) M(15) M(16) M(17) M(18) M(19) M(20) M(21) M(22) M(23) M(24) M(25)   \
  M(26) M(27) M(28) M(29) M(30) M(31) M(32) M(33) M(34) M(35) M(36) M(37)   \
  M(38) M(39) M(40) M(41) M(42) M(43) M(44) M(45) M(46) M(47) M(48) M(49)   \
  M(50) M(51) M(52) M(53) M(54) M(55) M(56) M(57) M(58) M(59) M(60) M(61)   \
  M(62) M(63)

#define WDECL(i) float wA##i, wB##i, wC##i, wD##i;

#define WLOADPIN(i)                                                          \
  { const float4 v_ = w4[i];                                                 \
    asm volatile("v_accvgpr_write_b32 %0, %1" : "=a"(wA##i) : "v"(v_.x));    \
    asm volatile("v_accvgpr_write_b32 %0, %1" : "=a"(wB##i) : "v"(v_.y));    \
    asm volatile("v_accvgpr_write_b32 %0, %1" : "=a"(wC##i) : "v"(v_.z));    \
    asm volatile("v_accvgpr_write_b32 %0, %1" : "=a"(wD##i) : "v"(v_.w)); }

// z-step quad: k = 64g + j0 .. +3, i = k/4. conv[k] comes from v_readlane of
// the per-lane conv pickup register cb{g} (VALU broadcast, no LDS traffic);
// weight from AGPR (volatile class-locked read). Ascending k, fused FMA:
// bit-identical chain to R1-R10.
#define ZQ(g, i, j0)                                                         \
  { float wa_, wb_, wc_, wd_;                                                \
    asm volatile("v_accvgpr_read_b32 %0, %1" : "=v"(wa_) : "a"(wA##i));      \
    asm volatile("v_accvgpr_read_b32 %0, %1" : "=v"(wb_) : "a"(wB##i));      \
    asm volatile("v_accvgpr_read_b32 %0, %1" : "=v"(wc_) : "a"(wC##i));      \
    asm volatile("v_accvgpr_read_b32 %0, %1" : "=v"(wd_) : "a"(wD##i));      \
    zacc = __builtin_fmaf(__uint_as_float((uint32_t)__builtin_amdgcn_readlane((int)cb##g, (j0)+0)), wa_, zacc); \
    zacc = __builtin_fmaf(__uint_as_float((uint32_t)__builtin_amdgcn_readlane((int)cb##g, (j0)+1)), wb_, zacc); \
    zacc = __builtin_fmaf(__uint_as_float((uint32_t)__builtin_amdgcn_readlane((int)cb##g, (j0)+2)), wc_, zacc); \
    zacc = __builtin_fmaf(__uint_as_float((uint32_t)__builtin_amdgcn_readlane((int)cb##g, (j0)+3)), wd_, zacc); }

#define ZG0 ZQ(0,0,0) ZQ(0,1,4) ZQ(0,2,8) ZQ(0,3,12) ZQ(0,4,16) ZQ(0,5,20) \
            ZQ(0,6,24) ZQ(0,7,28) ZQ(0,8,32) ZQ(0,9,36) ZQ(0,10,40)        \
            ZQ(0,11,44) ZQ(0,12,48) ZQ(0,13,52) ZQ(0,14,56) ZQ(0,15,60)
#define ZG1 ZQ(1,16,0) ZQ(1,17,4) ZQ(1,18,8) ZQ(1,19,12) ZQ(1,20,16)       \
            ZQ(1,21,20) ZQ(1,22,24) ZQ(1,23,28) ZQ(1,24,32) ZQ(1,25,36)    \
            ZQ(1,26,40) ZQ(1,27,44) ZQ(1,28,48) ZQ(1,29,52) ZQ(1,30,56) ZQ(1,31,60)
#define ZG2 ZQ(2,32,0) ZQ(2,33,4) ZQ(2,34,8) ZQ(2,35,12) ZQ(2,36,16)       \
            ZQ(2,37,20) ZQ(2,38,24) ZQ(2,39,28) ZQ(2,40,32) ZQ(2,41,36)    \
            ZQ(2,42,40) ZQ(2,43,44) ZQ(2,44,48) ZQ(2,45,52) ZQ(2,46,56) ZQ(2,47,60)
#define ZG3 ZQ(3,48,0) ZQ(3,49,4) ZQ(3,50,8) ZQ(3,51,12) ZQ(3,52,16)       \
            ZQ(3,53,20) ZQ(3,54,24) ZQ(3,55,28) ZQ(3,56,32) ZQ(3,57,36)    \
            ZQ(3,58,40) ZQ(3,59,44) ZQ(3,60,48) ZQ(3,61,52) ZQ(3,62,56) ZQ(3,63,60)

// ============================================================================
// Kernel 2: main simulation over [t0, t1). MODE 1 = S-table Poisson (+ rare
// inline continuation); MODE 0 = inline Poisson fallback.
// ============================================================================
template <int MODE>
__global__ __launch_bounds__(256, 1)
void poglm_main(const float* __restrict__ basis, const float* __restrict__ weight,
                const float* __restrict__ bias, const uint32_t* __restrict__ sub,
                float* __restrict__ out, const float* __restrict__ S8,
                float* __restrict__ histws, int t0, int t1) {
  __shared__ alignas(16) float convb[2][N_NEUR];
  __shared__ uint32_t skb[2][2 * J_MAX];
  __shared__ float fb[20];

  const int s = blockIdx.x;
  const int n = threadIdx.x;
  const int l = n & 63;  // lane

  if (n < 20) fb[n] = basis[19 - n];
  const float bias_n = bias[n];

  // Whole weight row (256 scalars) resident in AGPRs (def+use class-locked).
  const float4* __restrict__ w4 =
      reinterpret_cast<const float4*>(weight + (size_t)n * N_NEUR);
  FOR64(WDECL)
  FOR64(WLOADPIN)

  const uint32_t idx = (uint32_t)(s * N_NEUR + n);

  float hist[20];
  if (t0 == 0) {
#pragma unroll
    for (int i = 0; i < 20; ++i) hist[i] = 0.0f;
  } else {
#pragma unroll
    for (int i = 0; i < 20; ++i) hist[i] = histws[i * LANES + idx];
  }

  const size_t plane = (size_t)N_SAMP * T_BINS * N_NEUR;
  float* __restrict__ out_spk = out + 0 * plane + (size_t)s * T_BINS * N_NEUR + n;
  float* __restrict__ out_cnv = out + 1 * plane + (size_t)s * T_BINS * N_NEUR + n;
  float* __restrict__ out_rte = out + 2 * plane + (size_t)s * T_BINS * N_NEUR + n;

  uint32_t skreg = 0;
  float4 sc0, sc1;
  if constexpr (MODE == 0) {
    if (n < 2 * J_MAX) skreg = sub[(size_t)t0 * (2 * J_MAX) + n];
  } else {
    const float4* p = reinterpret_cast<const float4*>(S8 + (size_t)idx * J_PRE);
    sc0 = p[0]; sc1 = p[1];
  }

  __syncthreads();  // fb visible

  for (int t = t0; t < t1; ++t) {
    const int buf = t & 1;
    float* __restrict__ convbuf = convb[buf];

    float4 sn0, sn1;
    if constexpr (MODE == 0) {
      uint32_t* __restrict__ skbuf = skb[buf];
      if (n < 2 * J_MAX) {
        skbuf[n] = skreg;
        const int tn = (t + 1 < t1) ? t + 1 : t;
        skreg = sub[(size_t)tn * (2 * J_MAX) + n];
      }
    } else {
      const int tn = (t + 1 < t1) ? t + 1 : t;
      const float4* p = reinterpret_cast<const float4*>(
          S8 + ((size_t)(tn - t0) * LANES + idx) * J_PRE);
      sn0 = p[0]; sn1 = p[1];
    }

    // conv: ascending w, unfused mul+add (order bit-locked)
    float conv = 0.0f;
#pragma unroll
    for (int w = 0; w < 20; ++w) {
#if CONV_FMA
      conv = __builtin_fmaf(fb[w], hist[w], conv);
#else
      conv = fadd_s(conv, fmul_s(fb[w], hist[w]));
#endif
    }
    convbuf[n] = conv;

#if RAW_BARRIER
    asm volatile("s_waitcnt lgkmcnt(0)\n\ts_barrier" ::: "memory");
#else
    __syncthreads();
#endif

    // conv pickup: 4 conflict-free b32 reads/lane (2 lanes/bank = free),
    // then broadcast via v_readlane (VALU pipe) inside the z chain.
    const uint32_t cb0 = __float_as_uint(convbuf[l]);
    const uint32_t cb1 = __float_as_uint(convbuf[64 + l]);
    const uint32_t cb2 = __float_as_uint(convbuf[128 + l]);
    const uint32_t cb3 = __float_as_uint(convbuf[192 + l]);

    // z = sum_k conv[k]*W[n][k], fused FMA ascending k (order bit-locked).
    float zacc = 0.0f;
    ZG0 ZG1 ZG2 ZG3
    const float zb = fadd_s(zacc, bias_n);

    // lam = 1 / (1 + exp(-z))
    const float lam = 1.0f / fadd_s(1.0f, xla_expf(-zb));
    const float neg_lam = -lam;

    int r = 0;
    if constexpr (MODE == 1) {
      // S_j strictly non-increasing -> consecutive-count == count-all.
      r = (sc0.x > neg_lam) + (sc0.y > neg_lam) + (sc0.z > neg_lam) +
          (sc0.w > neg_lam) + (sc1.x > neg_lam) + (sc1.y > neg_lam) +
          (sc1.z > neg_lam) + (sc1.w > neg_lam);
      if (sc1.w > neg_lam) {  // rare (P <= 1e-5): continue the exact chain
        float S = sc1.w;
#pragma unroll 1
        for (int j = J_PRE; j < J_MAX; ++j) {
          const uint32_t k0 = sub[(size_t)t * (2 * J_MAX) + 2 * j];
          const uint32_t k1 = sub[(size_t)t * (2 * J_MAX) + 2 * j + 1];
          uint32_t o0, o1;
          threefry2x32(k0, k1, 0u, idx, o0, o1);
#if BITS32_XOR
          const uint32_t bits = o0 ^ o1;
#else
          const uint32_t bits = o1;
#endif
          const float u = __uint_as_float((bits >> 9) | 0x3f800000u) - 1.0f;
          S = fadd_s(S, xla_logf(u));
          if (S > neg_lam) ++r; else break;
        }
      }
    } else {
      uint32_t* __restrict__ skbuf = skb[buf];
      float S = 0.0f;
      bool done = false;
#pragma unroll 1
      for (int jb = 0; jb < J_MAX; jb += POISSON_BATCH) {
        float L[POISSON_BATCH];
#pragma unroll
        for (int q = 0; q < POISSON_BATCH; ++q) {
          const int j = jb + q;
          uint32_t o0, o1;
          threefry2x32(skbuf[2 * j], skbuf[2 * j + 1], 0u, idx, o0, o1);
#if BITS32_XOR
          const uint32_t bits = o0 ^ o1;
#else
          const uint32_t bits = o1;
#endif
          const float u = __uint_as_float((bits >> 9) | 0x3f800000u) - 1.0f;
          L[q] = xla_logf(u);
        }
#pragma unroll
        for (int q = 0; q < POISSON_BATCH; ++q) {
          if (!done) {
            S = fadd_s(S, L[q]);
            if (S > neg_lam) ++r; else done = true;
          }
        }
        if (__all(done)) break;
      }
    }
    const float spk = (float)r;

#pragma unroll
    for (int i = 0; i < 19; ++i) hist[i] = hist[i + 1];
    hist[19] = spk;

    const size_t off = (size_t)t * N_NEUR;
#if NT_STORES
    __builtin_nontemporal_store(spk,  out_spk + off);
    __builtin_nontemporal_store(conv, out_cnv + off);
    __builtin_nontemporal_store(lam,  out_rte + off);
#else
    out_spk[off] = spk;
    out_cnv[off] = conv;
    out_rte[off] = lam;
#endif
    if constexpr (MODE == 1) { sc0 = sn0; sc1 = sn1; }
#if !RAW_BARRIER
    __syncthreads();
#endif
  }

  // Chunk handoff: persist hist for the next launch.
  if (t1 < T_BINS) {
#pragma unroll
    for (int i = 0; i < 20; ++i) histws[i * LANES + idx] = hist[i];
  }
}

extern "C" void kernel_launch(void* const* d_in, const int* in_sizes, int n_in,
                              void* d_out, int out_size, void* d_ws, size_t ws_size,
                              hipStream_t stream) {
  const float* basis  = (const float*)d_in[0];
  const float* weight = (const float*)d_in[1];
  const float* bias   = (const float*)d_in[2];
  float* out = (float*)d_out;
  char* ws = (char*)d_ws;
  uint32_t* sub = (uint32_t*)ws;
  float* histws = (float*)(ws + HIST_OFF);
  float* stbl = (float*)(ws + STBL_OFF);

  hipLaunchKernelGGL(poglm_subkeys, dim3((T_BINS + 255) / 256), dim3(256), 0,
                     stream, sub);

  // Pick largest T-chunk whose S-table fits the workspace.
  int chunkT = 0;
  for (int c = T_BINS; c >= 64; c >>= 1) {
    const size_t bytes = (size_t)c * LANES * J_PRE * 4;
    if (STBL_OFF + bytes <= ws_size) { chunkT = c; break; }
  }

  if (chunkT == 0) {
    hipLaunchKernelGGL((poglm_main<0>), dim3(N_SAMP), dim3(256), 0,
                       stream, basis, weight, bias, sub, out,
                       (const float*)nullptr, histws, 0, T_BINS);
    return;
  }

  for (int t0 = 0; t0 < T_BINS; t0 += chunkT) {
    const int t1 = t0 + chunkT;
    hipLaunchKernelGGL(poglm_stable, dim3(chunkT * (LANES / 256)), dim3(256), 0,
                       stream, sub, stbl, t0);
    hipLaunchKernelGGL((poglm_main<1>), dim3(N_SAMP), dim3(256), 0,
                       stream, basis, weight, bias, sub, out,
                       (const float*)stbl, histws, t0, t1);
  }
}

// Round 13
// 1973.163 us; speedup vs baseline: 1.5626x; 1.5626x over previous
//
#include <hip/hip_runtime.h>
#include <stdint.h>
#include <math.h>

// ============================================================================
// POGLM.sample — bit-exact replication of the JAX-CPU reference.
// R13: (a) fused kernel — main blocks (0..63) simulate chunk c while extra
//      blocks compute chunk c+1's S-prefix table on the otherwise-idle CUs
//      (double-buffered in ws); only chunk 0's table is exposed (~50us).
//      (b) z-chain chunk restructure: 8 ds_read -> 32 accvgpr_read -> 32 FMA
//      (reads batched >=64cy ahead; R10 placed them ~8cy ahead).
//      R12 lesson: gfx950 VALU cannot source AGPRs directly (compile error);
//      v_accvgpr_read is mandatory. Arithmetic identical to passing R1-R11.
// Variant knobs:
#define THREEFRY_PARTITIONABLE 1
#define BITS32_XOR 1
#define VSL_FMA 0
#define CONV_FMA 0
#define RAW_BARRIER 1
#define POISSON_BATCH 4   // inline-path batch (MODE 0 fallback)
#define NT_STORES 1
#define J_PRE 8           // precomputed prefix depth
// ============================================================================

#define T_BINS 1024
#define N_SAMP 64
#define N_NEUR 256
#define J_MAX 32
#define LANES (N_SAMP * N_NEUR)  // 16384

// d_ws layout:
//   [0, 256KB)       sub: [1024][32][2] u32
//   [+, +1.25MB)     hist: [20][16384] f32 (chunk handoff)
//   [STBL_OFF, ...)  S-table: 2 buffers x chunkT x 16384 x 8 f32 (double-buf)
#define SUB_BYTES   (T_BINS * 2 * J_MAX * 4)
#define HIST_OFF    SUB_BYTES
#define HIST_BYTES  (20 * LANES * 4)
#define STBL_OFF    (HIST_OFF + HIST_BYTES)

// --- strict (non-contractable) f32 ops ---
static __device__ __forceinline__ float fmul_s(float a, float b) {
#pragma clang fp contract(off)
  return a * b;
}
static __device__ __forceinline__ float fadd_s(float a, float b) {
#pragma clang fp contract(off)
  return a + b;
}
static __device__ __forceinline__ float fsub_s(float a, float b) {
#pragma clang fp contract(off)
  return a - b;
}

#if VSL_FMA
#define MULADD(a, b, c) __builtin_fmaf((a), (b), (c))
#else
#define MULADD(a, b, c) fadd_s(fmul_s((a), (b)), (c))
#endif

// --- Threefry-2x32, 20 rounds (exact JAX semantics) ---
static __device__ __forceinline__ uint32_t rotl(uint32_t v, uint32_t d) {
  return (v << d) | (v >> (32u - d));
}
static __device__ __forceinline__ void threefry2x32(uint32_t k0, uint32_t k1,
                                                    uint32_t x0, uint32_t x1,
                                                    uint32_t& o0, uint32_t& o1) {
  const uint32_t k2 = k0 ^ k1 ^ 0x1BD11BDAu;
  x0 += k0; x1 += k1;
#define TF_RD(r) { x0 += x1; x1 = rotl(x1, r); x1 ^= x0; }
  TF_RD(13u) TF_RD(15u) TF_RD(26u) TF_RD(6u)
  x0 += k1; x1 += k2 + 1u;
  TF_RD(17u) TF_RD(29u) TF_RD(16u) TF_RD(24u)
  x0 += k2; x1 += k0 + 2u;
  TF_RD(13u) TF_RD(15u) TF_RD(26u) TF_RD(6u)
  x0 += k0; x1 += k1 + 3u;
  TF_RD(17u) TF_RD(29u) TF_RD(16u) TF_RD(24u)
  x0 += k1; x1 += k2 + 4u;
  TF_RD(13u) TF_RD(15u) TF_RD(26u) TF_RD(6u)
  x0 += k2; x1 += k0 + 5u;
#undef TF_RD
  o0 = x0; o1 = x1;
}

// --- XLA CPU Cephes expf (GenerateVF32Exp) ---
static __device__ __forceinline__ float xla_expf(float input) {
  float x = fminf(input, 88.3762626647950f);
  x = fmaxf(x, -88.3762626647949f);
  float fx = floorf(MULADD(x, 1.44269504088896341f, 0.5f));
  float tmp = fmul_s(0.693359375f, fx);
  float z = fmul_s(-2.12194440e-4f, fx);
  x = fsub_s(x, tmp);
  x = fsub_s(x, z);
  z = fmul_s(x, x);
  float y = MULADD(x, 1.9875691500e-4f, 1.3981999507e-3f);
  y = MULADD(y, x, 8.3334519073e-3f);
  y = MULADD(y, x, 4.1665795894e-2f);
  y = MULADD(y, x, 1.6666665459e-1f);
  y = MULADD(y, x, 5.0000001201e-1f);
  y = MULADD(y, z, x);
  y = fadd_s(1.0f, y);
  int n = (int)fx;
  float p2n = __int_as_float((uint32_t)(n + 127) << 23);
  float res = fmul_s(y, p2n);
  return fmaxf(res, input);
}

// --- XLA CPU Cephes logf (GenerateVF32Log); u in {0} U [2^-23, 1) here ---
static __device__ __forceinline__ float xla_logf(float u) {
  if (u == 0.0f) return -INFINITY;
  uint32_t b = __float_as_uint(u);
  float e = (float)((int)(b >> 23) - 127) + 1.0f;
  float m = __uint_as_float((b & 0x007fffffu) | 0x3f000000u);
  if (m < 0.707106781186547524f) {
    e = fsub_s(e, 1.0f);
    m = fadd_s(m, m);
  }
  m = fsub_s(m, 1.0f);
  float z = fmul_s(m, m);
  float y = MULADD(m, 7.0376836292e-2f, -1.1514610310e-1f);
  y = MULADD(y, m, 1.1676998740e-1f);
  y = MULADD(y, m, -1.2420140846e-1f);
  y = MULADD(y, m, 1.4249322787e-1f);
  y = MULADD(y, m, -1.6668057665e-1f);
  y = MULADD(y, m, 2.0000714765e-1f);
  y = MULADD(y, m, -2.4999993993e-1f);
  y = MULADD(y, m, 3.3333331174e-1f);
  y = fmul_s(y, m);
  y = fmul_s(y, z);
  y = MULADD(e, -2.12194440e-4f, y);
  y = MULADD(z, -0.5f, y);
  m = fadd_s(m, y);
  m = MULADD(e, 0.693359375f, m);
  return m;
}

// Shared S-prefix computation: 8 draws for (tt, ln), byte-identical chain.
static __device__ __forceinline__ void stable_body(
    const uint32_t* __restrict__ sub, float* __restrict__ dst8,
    int tt, int ln) {
  float S = 0.0f;
  float v[J_PRE];
#pragma unroll
  for (int j = 0; j < J_PRE; ++j) {
    const uint32_t k0 = sub[(size_t)tt * (2 * J_MAX) + 2 * j];
    const uint32_t k1 = sub[(size_t)tt * (2 * J_MAX) + 2 * j + 1];
    uint32_t o0, o1;
    threefry2x32(k0, k1, 0u, (uint32_t)ln, o0, o1);
#if BITS32_XOR
    const uint32_t bits = o0 ^ o1;
#else
    const uint32_t bits = o1;
#endif
    const float u = __uint_as_float((bits >> 9) | 0x3f800000u) - 1.0f;
    S = fadd_s(S, xla_logf(u));
    v[j] = S;
  }
  float4* dst = reinterpret_cast<float4*>(dst8);
  dst[0] = make_float4(v[0], v[1], v[2], v[3]);
  dst[1] = make_float4(v[4], v[5], v[6], v[7]);
}

// ============================================================================
// Kernel 1: per-time-step subkey chains. sub layout: [t][j][2] u32.
// ============================================================================
__global__ void poglm_subkeys(uint32_t* __restrict__ sub) {
  int t = blockIdx.x * blockDim.x + threadIdx.x;
  if (t >= T_BINS) return;
  uint32_t kt0, kt1;
#if THREEFRY_PARTITIONABLE
  threefry2x32(0u, 1u, 0u, (uint32_t)t, kt0, kt1);
#else
  {
    uint32_t i0 = 2u * t, i1 = 2u * t + 1u, a0, a1, b0, b1;
    if (i0 < 1024u) { threefry2x32(0u, 1u, i0, i0 + 1024u, a0, a1); kt0 = a0; }
    else            { threefry2x32(0u, 1u, i0 - 1024u, i0, a0, a1); kt0 = a1; }
    if (i1 < 1024u) { threefry2x32(0u, 1u, i1, i1 + 1024u, b0, b1); kt1 = b0; }
    else            { threefry2x32(0u, 1u, i1 - 1024u, i1, b0, b1); kt1 = b1; }
  }
#endif
  uint32_t r0 = kt0, r1 = kt1;
  for (int j = 0; j < J_MAX; ++j) {
    uint32_t s0, s1, n0, n1;
#if THREEFRY_PARTITIONABLE
    threefry2x32(r0, r1, 0u, 1u, s0, s1);
    threefry2x32(r0, r1, 0u, 0u, n0, n1);
#else
    uint32_t p00, p01, p10, p11;
    threefry2x32(r0, r1, 0u, 2u, p00, p01);
    threefry2x32(r0, r1, 1u, 3u, p10, p11);
    n0 = p00; n1 = p10;
    s0 = p01; s1 = p11;
#endif
    sub[(size_t)t * (2 * J_MAX) + 2 * j + 0] = s0;
    sub[(size_t)t * (2 * J_MAX) + 2 * j + 1] = s1;
    r0 = n0; r1 = n1;
  }
}

// ============================================================================
// Kernel 1b: standalone S-prefix table (small footprint, high occupancy) —
// used only for chunk 0. S8[((t-t0)*LANES + idx)*8 + j].
// ============================================================================
__global__ __launch_bounds__(256)
void poglm_stable(const uint32_t* __restrict__ sub, float* __restrict__ S8,
                  int t0) {
  const int g  = blockIdx.x * 256 + threadIdx.x;
  const int tt = t0 + g / LANES;
  const int ln = g % LANES;
  stable_body(sub, S8 + (size_t)g * J_PRE, tt, ln);
}

// ---- 64 x float4 = 256 AGPR-resident weights --------------------------------
#define FOR64(M) \
  M(0) M(1) M(2) M(3) M(4) M(5) M(6) M(7) M(8) M(9) M(10) M(11) M(12) M(13) \
  M(14) M(15) M(16) M(17) M(18) M(19) M(20) M(21) M(22) M(23) M(24) M(25)   \
  M(26) M(27) M(28) M(29) M(30) M(31) M(32) M(33) M(34) M(35) M(36) M(37)   \
  M(38) M(39) M(40) M(41) M(42) M(43) M(44) M(45) M(46) M(47) M(48) M(49)   \
  M(50) M(51) M(52) M(53) M(54) M(55) M(56) M(57) M(58) M(59) M(60) M(61)   \
  M(62) M(63)

#define WDECL(i) float wA##i, wB##i, wC##i, wD##i;

#define WLOADPIN(i)                                                          \
  { const float4 v_ = w4[i];                                                 \
    asm volatile("v_accvgpr_write_b32 %0, %1" : "=a"(wA##i) : "v"(v_.x));    \
    asm volatile("v_accvgpr_write_b32 %0, %1" : "=a"(wB##i) : "v"(v_.y));    \
    asm volatile("v_accvgpr_write_b32 %0, %1" : "=a"(wC##i) : "v"(v_.z));    \
    asm volatile("v_accvgpr_write_b32 %0, %1" : "=a"(wD##i) : "v"(v_.w)); }

// z-chunk of 32 k-values: batch-issue 8 ds_read_b128, then ALL 32 volatile
// accvgpr_reads (>=64cy ahead of first use), then the 32 FMAs in ascending-k
// order. Chain values bit-identical to R1-R11.
#define LOADCV(u, i) const float4 cv##u = convbuf4[i];
#define AREAD(u, i)                                                          \
  float ta##u, tb##u, tc##u, td##u;                                          \
  asm volatile("v_accvgpr_read_b32 %0, %1" : "=v"(ta##u) : "a"(wA##i));      \
  asm volatile("v_accvgpr_read_b32 %0, %1" : "=v"(tb##u) : "a"(wB##i));      \
  asm volatile("v_accvgpr_read_b32 %0, %1" : "=v"(tc##u) : "a"(wC##i));      \
  asm volatile("v_accvgpr_read_b32 %0, %1" : "=v"(td##u) : "a"(wD##i));
#define FMA4(u)                                                              \
  zacc = __builtin_fmaf(cv##u.x, ta##u, zacc);                               \
  zacc = __builtin_fmaf(cv##u.y, tb##u, zacc);                               \
  zacc = __builtin_fmaf(cv##u.z, tc##u, zacc);                               \
  zacc = __builtin_fmaf(cv##u.w, td##u, zacc);

#define ZCHUNK(i0,i1,i2,i3,i4,i5,i6,i7)                                      \
  { LOADCV(0,i0) LOADCV(1,i1) LOADCV(2,i2) LOADCV(3,i3)                      \
    LOADCV(4,i4) LOADCV(5,i5) LOADCV(6,i6) LOADCV(7,i7)                      \
    AREAD(0,i0) AREAD(1,i1) AREAD(2,i2) AREAD(3,i3)                          \
    AREAD(4,i4) AREAD(5,i5) AREAD(6,i6) AREAD(7,i7)                          \
    FMA4(0) FMA4(1) FMA4(2) FMA4(3) FMA4(4) FMA4(5) FMA4(6) FMA4(7) }

// ============================================================================
// Kernel 2 (fused): blocks [0,64) = main simulation over [t0,t1) using S8_in;
// blocks [64, 64+nstb) = S-table for [tb0, tb0+chunkT) into S8_out.
// MODE 1 = S-table Poisson; MODE 0 = inline Poisson fallback (grid = 64).
// ============================================================================
template <int MODE>
__global__ __launch_bounds__(256, 1)
void poglm_fused(const float* __restrict__ basis, const float* __restrict__ weight,
                 const float* __restrict__ bias, const uint32_t* __restrict__ sub,
                 float* __restrict__ out, const float* __restrict__ S8_in,
                 float* __restrict__ S8_out, int tb0,
                 float* __restrict__ histws, int t0, int t1) {
  if (MODE == 1 && blockIdx.x >= N_SAMP) {
    // ---- stable path: compute next chunk's S-prefixes ----
    const int g  = (blockIdx.x - N_SAMP) * 256 + threadIdx.x;
    const int tt = tb0 + g / LANES;
    const int ln = g % LANES;
    stable_body(sub, S8_out + (size_t)g * J_PRE, tt, ln);
    return;
  }

  __shared__ alignas(16) float convb[2][N_NEUR];
  __shared__ uint32_t skb[2][2 * J_MAX];
  __shared__ float fb[20];

  const int s = blockIdx.x;
  const int n = threadIdx.x;

  if (n < 20) fb[n] = basis[19 - n];
  const float bias_n = bias[n];

  // Whole weight row (256 scalars) resident in AGPRs (def+use class-locked).
  const float4* __restrict__ w4 =
      reinterpret_cast<const float4*>(weight + (size_t)n * N_NEUR);
  FOR64(WDECL)
  FOR64(WLOADPIN)

  const uint32_t idx = (uint32_t)(s * N_NEUR + n);

  float hist[20];
  if (t0 == 0) {
#pragma unroll
    for (int i = 0; i < 20; ++i) hist[i] = 0.0f;
  } else {
#pragma unroll
    for (int i = 0; i < 20; ++i) hist[i] = histws[i * LANES + idx];
  }

  const size_t plane = (size_t)N_SAMP * T_BINS * N_NEUR;
  float* __restrict__ out_spk = out + 0 * plane + (size_t)s * T_BINS * N_NEUR + n;
  float* __restrict__ out_cnv = out + 1 * plane + (size_t)s * T_BINS * N_NEUR + n;
  float* __restrict__ out_rte = out + 2 * plane + (size_t)s * T_BINS * N_NEUR + n;

  uint32_t skreg = 0;
  float4 sc0, sc1;
  if constexpr (MODE == 0) {
    if (n < 2 * J_MAX) skreg = sub[(size_t)t0 * (2 * J_MAX) + n];
  } else {
    const float4* p = reinterpret_cast<const float4*>(S8_in + (size_t)idx * J_PRE);
    sc0 = p[0]; sc1 = p[1];
  }

  __syncthreads();  // fb visible

  for (int t = t0; t < t1; ++t) {
    const int buf = t & 1;
    float* __restrict__ convbuf = convb[buf];
    const float4* __restrict__ convbuf4 = reinterpret_cast<const float4*>(convbuf);

    float4 sn0, sn1;
    if constexpr (MODE == 0) {
      uint32_t* __restrict__ skbuf = skb[buf];
      if (n < 2 * J_MAX) {
        skbuf[n] = skreg;
        const int tn = (t + 1 < t1) ? t + 1 : t;
        skreg = sub[(size_t)tn * (2 * J_MAX) + n];
      }
    } else {
      const int tn = (t + 1 < t1) ? t + 1 : t;
      const float4* p = reinterpret_cast<const float4*>(
          S8_in + ((size_t)(tn - t0) * LANES + idx) * J_PRE);
      sn0 = p[0]; sn1 = p[1];
    }

    // conv: ascending w, unfused mul+add (order bit-locked)
    float conv = 0.0f;
#pragma unroll
    for (int w = 0; w < 20; ++w) {
#if CONV_FMA
      conv = __builtin_fmaf(fb[w], hist[w], conv);
#else
      conv = fadd_s(conv, fmul_s(fb[w], hist[w]));
#endif
    }
    convbuf[n] = conv;

#if RAW_BARRIER
    asm volatile("s_waitcnt lgkmcnt(0)\n\ts_barrier" ::: "memory");
#else
    __syncthreads();
#endif

    // z = sum_k conv[k]*W[n][k], fused FMA ascending k (order bit-locked).
    float zacc = 0.0f;
    ZCHUNK(0,1,2,3,4,5,6,7)
    ZCHUNK(8,9,10,11,12,13,14,15)
    ZCHUNK(16,17,18,19,20,21,22,23)
    ZCHUNK(24,25,26,27,28,29,30,31)
    ZCHUNK(32,33,34,35,36,37,38,39)
    ZCHUNK(40,41,42,43,44,45,46,47)
    ZCHUNK(48,49,50,51,52,53,54,55)
    ZCHUNK(56,57,58,59,60,61,62,63)
    const float zb = fadd_s(zacc, bias_n);

    // lam = 1 / (1 + exp(-z))
    const float lam = 1.0f / fadd_s(1.0f, xla_expf(-zb));
    const float neg_lam = -lam;

    int r = 0;
    if constexpr (MODE == 1) {
      // S_j strictly non-increasing -> consecutive-count == count-all.
      r = (sc0.x > neg_lam) + (sc0.y > neg_lam) + (sc0.z > neg_lam) +
          (sc0.w > neg_lam) + (sc1.x > neg_lam) + (sc1.y > neg_lam) +
          (sc1.z > neg_lam) + (sc1.w > neg_lam);
      if (sc1.w > neg_lam) {  // rare (P <= 1e-5): continue the exact chain
        float S = sc1.w;
#pragma unroll 1
        for (int j = J_PRE; j < J_MAX; ++j) {
          const uint32_t k0 = sub[(size_t)t * (2 * J_MAX) + 2 * j];
          const uint32_t k1 = sub[(size_t)t * (2 * J_MAX) + 2 * j + 1];
          uint32_t o0, o1;
          threefry2x32(k0, k1, 0u, idx, o0, o1);
#if BITS32_XOR
          const uint32_t bits = o0 ^ o1;
#else
          const uint32_t bits = o1;
#endif
          const float u = __uint_as_float((bits >> 9) | 0x3f800000u) - 1.0f;
          S = fadd_s(S, xla_logf(u));
          if (S > neg_lam) ++r; else break;
        }
      }
    } else {
      uint32_t* __restrict__ skbuf = skb[buf];
      float S = 0.0f;
      bool done = false;
#pragma unroll 1
      for (int jb = 0; jb < J_MAX; jb += POISSON_BATCH) {
        float L[POISSON_BATCH];
#pragma unroll
        for (int q = 0; q < POISSON_BATCH; ++q) {
          const int j = jb + q;
          uint32_t o0, o1;
          threefry2x32(skbuf[2 * j], skbuf[2 * j + 1], 0u, idx, o0, o1);
#if BITS32_XOR
          const uint32_t bits = o0 ^ o1;
#else
          const uint32_t bits = o1;
#endif
          const float u = __uint_as_float((bits >> 9) | 0x3f800000u) - 1.0f;
          L[q] = xla_logf(u);
        }
#pragma unroll
        for (int q = 0; q < POISSON_BATCH; ++q) {
          if (!done) {
            S = fadd_s(S, L[q]);
            if (S > neg_lam) ++r; else done = true;
          }
        }
        if (__all(done)) break;
      }
    }
    const float spk = (float)r;

#pragma unroll
    for (int i = 0; i < 19; ++i) hist[i] = hist[i + 1];
    hist[19] = spk;

    const size_t off = (size_t)t * N_NEUR;
#if NT_STORES
    __builtin_nontemporal_store(spk,  out_spk + off);
    __builtin_nontemporal_store(conv, out_cnv + off);
    __builtin_nontemporal_store(lam,  out_rte + off);
#else
    out_spk[off] = spk;
    out_cnv[off] = conv;
    out_rte[off] = lam;
#endif
    if constexpr (MODE == 1) { sc0 = sn0; sc1 = sn1; }
#if !RAW_BARRIER
    __syncthreads();
#endif
  }

  // Chunk handoff: persist hist for the next launch.
  if (t1 < T_BINS) {
#pragma unroll
    for (int i = 0; i < 20; ++i) histws[i * LANES + idx] = hist[i];
  }
}

extern "C" void kernel_launch(void* const* d_in, const int* in_sizes, int n_in,
                              void* d_out, int out_size, void* d_ws, size_t ws_size,
                              hipStream_t stream) {
  const float* basis  = (const float*)d_in[0];
  const float* weight = (const float*)d_in[1];
  const float* bias   = (const float*)d_in[2];
  float* out = (float*)d_out;
  char* ws = (char*)d_ws;
  uint32_t* sub = (uint32_t*)ws;
  float* histws = (float*)(ws + HIST_OFF);

  hipLaunchKernelGGL(poglm_subkeys, dim3((T_BINS + 255) / 256), dim3(256), 0,
                     stream, sub);

  // Pick chunkT for DOUBLE-buffered S-table (prefer 256: table fits L3, 4
  // fused launches, only chunk 0's table exposed).
  int chunkT = 0;
  const int cand[4] = {256, 512, 128, 64};
  for (int ci = 0; ci < 4; ++ci) {
    const size_t bytes = (size_t)cand[ci] * LANES * J_PRE * 4;
    if (STBL_OFF + 2 * bytes <= ws_size) { chunkT = cand[ci]; break; }
  }

  if (chunkT == 0) {
    // Workspace too small even for 2x64-step tables: single-buffer serial
    // (R9 path) or inline fallback.
    int sc = 0;
    for (int c = T_BINS; c >= 64; c >>= 1) {
      const size_t bytes = (size_t)c * LANES * J_PRE * 4;
      if (STBL_OFF + bytes <= ws_size) { sc = c; break; }
    }
    if (sc == 0) {
      hipLaunchKernelGGL((poglm_fused<0>), dim3(N_SAMP), dim3(256), 0,
                         stream, basis, weight, bias, sub, out,
                         (const float*)nullptr, (float*)nullptr, 0,
                         histws, 0, T_BINS);
      return;
    }
    float* stbl = (float*)(ws + STBL_OFF);
    for (int t0 = 0; t0 < T_BINS; t0 += sc) {
      hipLaunchKernelGGL(poglm_stable, dim3(sc * (LANES / 256)), dim3(256), 0,
                         stream, sub, stbl, t0);
      hipLaunchKernelGGL((poglm_fused<1>), dim3(N_SAMP), dim3(256), 0,
                         stream, basis, weight, bias, sub, out,
                         (const float*)stbl, (float*)nullptr, 0,
                         histws, t0, t0 + sc);
    }
    return;
  }

  const size_t stbl_bytes = (size_t)chunkT * LANES * J_PRE * 4;
  float* stbl0 = (float*)(ws + STBL_OFF);
  float* stbl1 = (float*)(ws + STBL_OFF + stbl_bytes);
  const int nstb = chunkT * (LANES / 256);  // stable blocks per chunk
  const int nc = T_BINS / chunkT;

  // Chunk 0's table: standalone high-occupancy kernel (exposed, ~50us).
  hipLaunchKernelGGL(poglm_stable, dim3(nstb), dim3(256), 0, stream,
                     sub, stbl0, 0);

  for (int c = 0; c < nc; ++c) {
    const int t0 = c * chunkT, t1 = t0 + chunkT;
    float* cur = (c & 1) ? stbl1 : stbl0;
    float* nxt = (c & 1) ? stbl0 : stbl1;
    const bool more = (c + 1 < nc);
    // Fused: 64 main blocks + (if more) nstb stable blocks for chunk c+1.
    hipLaunchKernelGGL((poglm_fused<1>),
                       dim3(N_SAMP + (more ? nstb : 0)), dim3(256), 0,
                       stream, basis, weight, bias, sub, out,
                       (const float*)cur, nxt, t1, histws, t0, t1);
  }
}

// Round 14
// 1946.971 us; speedup vs baseline: 1.5837x; 1.0135x over previous
//
#include <hip/hip_runtime.h>
#include <stdint.h>
#include <math.h>

// ============================================================================
// POGLM.sample — bit-exact replication of the JAX-CPU reference.
// R14: z-phase scheduling only (R13 fusion kept):
//      (a) ping-pong cv prefetch — chunk c+1's 8 ds_read_b128 issue before
//          chunk c's FMAs (read->use distance ~250cy, kills per-chunk lgkm
//          waits); (b) quad-granularity AREAD/FMA interleave (scheduler can
//          fill FMA dep-stall slots with independent AGPR reads).
//      Arithmetic identical to passing R1-R13 (absmax 0.0625).
// Variant knobs:
#define THREEFRY_PARTITIONABLE 1
#define BITS32_XOR 1
#define VSL_FMA 0
#define CONV_FMA 0
#define RAW_BARRIER 1
#define POISSON_BATCH 4   // inline-path batch (MODE 0 fallback)
#define NT_STORES 1
#define J_PRE 8           // precomputed prefix depth
// ============================================================================

#define T_BINS 1024
#define N_SAMP 64
#define N_NEUR 256
#define J_MAX 32
#define LANES (N_SAMP * N_NEUR)  // 16384

// d_ws layout:
#define SUB_BYTES   (T_BINS * 2 * J_MAX * 4)
#define HIST_OFF    SUB_BYTES
#define HIST_BYTES  (20 * LANES * 4)
#define STBL_OFF    (HIST_OFF + HIST_BYTES)

// --- strict (non-contractable) f32 ops ---
static __device__ __forceinline__ float fmul_s(float a, float b) {
#pragma clang fp contract(off)
  return a * b;
}
static __device__ __forceinline__ float fadd_s(float a, float b) {
#pragma clang fp contract(off)
  return a + b;
}
static __device__ __forceinline__ float fsub_s(float a, float b) {
#pragma clang fp contract(off)
  return a - b;
}

#if VSL_FMA
#define MULADD(a, b, c) __builtin_fmaf((a), (b), (c))
#else
#define MULADD(a, b, c) fadd_s(fmul_s((a), (b)), (c))
#endif

// --- Threefry-2x32, 20 rounds (exact JAX semantics) ---
static __device__ __forceinline__ uint32_t rotl(uint32_t v, uint32_t d) {
  return (v << d) | (v >> (32u - d));
}
static __device__ __forceinline__ void threefry2x32(uint32_t k0, uint32_t k1,
                                                    uint32_t x0, uint32_t x1,
                                                    uint32_t& o0, uint32_t& o1) {
  const uint32_t k2 = k0 ^ k1 ^ 0x1BD11BDAu;
  x0 += k0; x1 += k1;
#define TF_RD(r) { x0 += x1; x1 = rotl(x1, r); x1 ^= x0; }
  TF_RD(13u) TF_RD(15u) TF_RD(26u) TF_RD(6u)
  x0 += k1; x1 += k2 + 1u;
  TF_RD(17u) TF_RD(29u) TF_RD(16u) TF_RD(24u)
  x0 += k2; x1 += k0 + 2u;
  TF_RD(13u) TF_RD(15u) TF_RD(26u) TF_RD(6u)
  x0 += k0; x1 += k1 + 3u;
  TF_RD(17u) TF_RD(29u) TF_RD(16u) TF_RD(24u)
  x0 += k1; x1 += k2 + 4u;
  TF_RD(13u) TF_RD(15u) TF_RD(26u) TF_RD(6u)
  x0 += k2; x1 += k0 + 5u;
#undef TF_RD
  o0 = x0; o1 = x1;
}

// --- XLA CPU Cephes expf (GenerateVF32Exp) ---
static __device__ __forceinline__ float xla_expf(float input) {
  float x = fminf(input, 88.3762626647950f);
  x = fmaxf(x, -88.3762626647949f);
  float fx = floorf(MULADD(x, 1.44269504088896341f, 0.5f));
  float tmp = fmul_s(0.693359375f, fx);
  float z = fmul_s(-2.12194440e-4f, fx);
  x = fsub_s(x, tmp);
  x = fsub_s(x, z);
  z = fmul_s(x, x);
  float y = MULADD(x, 1.9875691500e-4f, 1.3981999507e-3f);
  y = MULADD(y, x, 8.3334519073e-3f);
  y = MULADD(y, x, 4.1665795894e-2f);
  y = MULADD(y, x, 1.6666665459e-1f);
  y = MULADD(y, x, 5.0000001201e-1f);
  y = MULADD(y, z, x);
  y = fadd_s(1.0f, y);
  int n = (int)fx;
  float p2n = __int_as_float((uint32_t)(n + 127) << 23);
  float res = fmul_s(y, p2n);
  return fmaxf(res, input);
}

// --- XLA CPU Cephes logf (GenerateVF32Log); u in {0} U [2^-23, 1) here ---
static __device__ __forceinline__ float xla_logf(float u) {
  if (u == 0.0f) return -INFINITY;
  uint32_t b = __float_as_uint(u);
  float e = (float)((int)(b >> 23) - 127) + 1.0f;
  float m = __uint_as_float((b & 0x007fffffu) | 0x3f000000u);
  if (m < 0.707106781186547524f) {
    e = fsub_s(e, 1.0f);
    m = fadd_s(m, m);
  }
  m = fsub_s(m, 1.0f);
  float z = fmul_s(m, m);
  float y = MULADD(m, 7.0376836292e-2f, -1.1514610310e-1f);
  y = MULADD(y, m, 1.1676998740e-1f);
  y = MULADD(y, m, -1.2420140846e-1f);
  y = MULADD(y, m, 1.4249322787e-1f);
  y = MULADD(y, m, -1.6668057665e-1f);
  y = MULADD(y, m, 2.0000714765e-1f);
  y = MULADD(y, m, -2.4999993993e-1f);
  y = MULADD(y, m, 3.3333331174e-1f);
  y = fmul_s(y, m);
  y = fmul_s(y, z);
  y = MULADD(e, -2.12194440e-4f, y);
  y = MULADD(z, -0.5f, y);
  m = fadd_s(m, y);
  m = MULADD(e, 0.693359375f, m);
  return m;
}

// Shared S-prefix computation: 8 draws for (tt, ln), byte-identical chain.
static __device__ __forceinline__ void stable_body(
    const uint32_t* __restrict__ sub, float* __restrict__ dst8,
    int tt, int ln) {
  float S = 0.0f;
  float v[J_PRE];
#pragma unroll
  for (int j = 0; j < J_PRE; ++j) {
    const uint32_t k0 = sub[(size_t)tt * (2 * J_MAX) + 2 * j];
    const uint32_t k1 = sub[(size_t)tt * (2 * J_MAX) + 2 * j + 1];
    uint32_t o0, o1;
    threefry2x32(k0, k1, 0u, (uint32_t)ln, o0, o1);
#if BITS32_XOR
    const uint32_t bits = o0 ^ o1;
#else
    const uint32_t bits = o1;
#endif
    const float u = __uint_as_float((bits >> 9) | 0x3f800000u) - 1.0f;
    S = fadd_s(S, xla_logf(u));
    v[j] = S;
  }
  float4* dst = reinterpret_cast<float4*>(dst8);
  dst[0] = make_float4(v[0], v[1], v[2], v[3]);
  dst[1] = make_float4(v[4], v[5], v[6], v[7]);
}

// ============================================================================
// Kernel 1: per-time-step subkey chains. sub layout: [t][j][2] u32.
// ============================================================================
__global__ void poglm_subkeys(uint32_t* __restrict__ sub) {
  int t = blockIdx.x * blockDim.x + threadIdx.x;
  if (t >= T_BINS) return;
  uint32_t kt0, kt1;
#if THREEFRY_PARTITIONABLE
  threefry2x32(0u, 1u, 0u, (uint32_t)t, kt0, kt1);
#else
  {
    uint32_t i0 = 2u * t, i1 = 2u * t + 1u, a0, a1, b0, b1;
    if (i0 < 1024u) { threefry2x32(0u, 1u, i0, i0 + 1024u, a0, a1); kt0 = a0; }
    else            { threefry2x32(0u, 1u, i0 - 1024u, i0, a0, a1); kt0 = a1; }
    if (i1 < 1024u) { threefry2x32(0u, 1u, i1, i1 + 1024u, b0, b1); kt1 = b0; }
    else            { threefry2x32(0u, 1u, i1 - 1024u, i1, b0, b1); kt1 = b1; }
  }
#endif
  uint32_t r0 = kt0, r1 = kt1;
  for (int j = 0; j < J_MAX; ++j) {
    uint32_t s0, s1, n0, n1;
#if THREEFRY_PARTITIONABLE
    threefry2x32(r0, r1, 0u, 1u, s0, s1);
    threefry2x32(r0, r1, 0u, 0u, n0, n1);
#else
    uint32_t p00, p01, p10, p11;
    threefry2x32(r0, r1, 0u, 2u, p00, p01);
    threefry2x32(r0, r1, 1u, 3u, p10, p11);
    n0 = p00; n1 = p10;
    s0 = p01; s1 = p11;
#endif
    sub[(size_t)t * (2 * J_MAX) + 2 * j + 0] = s0;
    sub[(size_t)t * (2 * J_MAX) + 2 * j + 1] = s1;
    r0 = n0; r1 = n1;
  }
}

// ============================================================================
// Kernel 1b: standalone S-prefix table — used only for chunk 0.
// ============================================================================
__global__ __launch_bounds__(256)
void poglm_stable(const uint32_t* __restrict__ sub, float* __restrict__ S8,
                  int t0) {
  const int g  = blockIdx.x * 256 + threadIdx.x;
  const int tt = t0 + g / LANES;
  const int ln = g % LANES;
  stable_body(sub, S8 + (size_t)g * J_PRE, tt, ln);
}

// ---- 64 x float4 = 256 AGPR-resident weights --------------------------------
#define FOR64(M) \
  M(0) M(1) M(2) M(3) M(4) M(5) M(6) M(7) M(8) M(9) M(10) M(11) M(12) M(13) \
  M(14) M(15) M(16) M(17) M(18) M(19) M(20) M(21) M(22) M(23) M(24) M(25)   \
  M(26) M(27) M(28) M(29) M(30) M(31) M(32) M(33) M(34) M(35) M(36) M(37)   \
  M(38) M(39) M(40) M(41) M(42) M(43) M(44) M(45) M(46) M(47) M(48) M(49)   \
  M(50) M(51) M(52) M(53) M(54) M(55) M(56) M(57) M(58) M(59) M(60) M(61)   \
  M(62) M(63)

#define WDECL(i) float wA##i, wB##i, wC##i, wD##i;

#define WLOADPIN(i)                                                          \
  { const float4 v_ = w4[i];                                                 \
    asm volatile("v_accvgpr_write_b32 %0, %1" : "=a"(wA##i) : "v"(v_.x));    \
    asm volatile("v_accvgpr_write_b32 %0, %1" : "=a"(wB##i) : "v"(v_.y));    \
    asm volatile("v_accvgpr_write_b32 %0, %1" : "=a"(wC##i) : "v"(v_.z));    \
    asm volatile("v_accvgpr_write_b32 %0, %1" : "=a"(wD##i) : "v"(v_.w)); }

// Quad: 4 volatile AGPR reads + 4 ascending-k fused FMAs (chain bit-locked).
#define QUAD(cvreg, i)                                                       \
  { float ta_, tb_, tc_, td_;                                                \
    asm volatile("v_accvgpr_read_b32 %0, %1" : "=v"(ta_) : "a"(wA##i));      \
    asm volatile("v_accvgpr_read_b32 %0, %1" : "=v"(tb_) : "a"(wB##i));      \
    asm volatile("v_accvgpr_read_b32 %0, %1" : "=v"(tc_) : "a"(wC##i));      \
    asm volatile("v_accvgpr_read_b32 %0, %1" : "=v"(td_) : "a"(wD##i));      \
    zacc = __builtin_fmaf(cvreg.x, ta_, zacc);                               \
    zacc = __builtin_fmaf(cvreg.y, tb_, zacc);                               \
    zacc = __builtin_fmaf(cvreg.z, tc_, zacc);                               \
    zacc = __builtin_fmaf(cvreg.w, td_, zacc); }

// Ping-pong cv sets: load chunk c+1's 8 float4 while computing chunk c.
#define ZLOAD_A(i0,i1,i2,i3,i4,i5,i6,i7)                                     \
  cvA0 = convbuf4[i0]; cvA1 = convbuf4[i1]; cvA2 = convbuf4[i2];             \
  cvA3 = convbuf4[i3]; cvA4 = convbuf4[i4]; cvA5 = convbuf4[i5];             \
  cvA6 = convbuf4[i6]; cvA7 = convbuf4[i7];
#define ZLOAD_B(i0,i1,i2,i3,i4,i5,i6,i7)                                     \
  cvB0 = convbuf4[i0]; cvB1 = convbuf4[i1]; cvB2 = convbuf4[i2];             \
  cvB3 = convbuf4[i3]; cvB4 = convbuf4[i4]; cvB5 = convbuf4[i5];             \
  cvB6 = convbuf4[i6]; cvB7 = convbuf4[i7];
#define ZCOMP_A(i0,i1,i2,i3,i4,i5,i6,i7)                                     \
  QUAD(cvA0,i0) QUAD(cvA1,i1) QUAD(cvA2,i2) QUAD(cvA3,i3)                    \
  QUAD(cvA4,i4) QUAD(cvA5,i5) QUAD(cvA6,i6) QUAD(cvA7,i7)
#define ZCOMP_B(i0,i1,i2,i3,i4,i5,i6,i7)                                     \
  QUAD(cvB0,i0) QUAD(cvB1,i1) QUAD(cvB2,i2) QUAD(cvB3,i3)                    \
  QUAD(cvB4,i4) QUAD(cvB5,i5) QUAD(cvB6,i6) QUAD(cvB7,i7)

// ============================================================================
// Kernel 2 (fused): blocks [0,64) = main simulation over [t0,t1) using S8_in;
// blocks [64, 64+nstb) = S-table for [tb0, tb0+chunkT) into S8_out.
// ============================================================================
template <int MODE>
__global__ __launch_bounds__(256, 1)
void poglm_fused(const float* __restrict__ basis, const float* __restrict__ weight,
                 const float* __restrict__ bias, const uint32_t* __restrict__ sub,
                 float* __restrict__ out, const float* __restrict__ S8_in,
                 float* __restrict__ S8_out, int tb0,
                 float* __restrict__ histws, int t0, int t1) {
  if (MODE == 1 && blockIdx.x >= N_SAMP) {
    const int g  = (blockIdx.x - N_SAMP) * 256 + threadIdx.x;
    const int tt = tb0 + g / LANES;
    const int ln = g % LANES;
    stable_body(sub, S8_out + (size_t)g * J_PRE, tt, ln);
    return;
  }

  __shared__ alignas(16) float convb[2][N_NEUR];
  __shared__ uint32_t skb[2][2 * J_MAX];
  __shared__ float fb[20];

  const int s = blockIdx.x;
  const int n = threadIdx.x;

  if (n < 20) fb[n] = basis[19 - n];
  const float bias_n = bias[n];

  // Whole weight row (256 scalars) resident in AGPRs (def+use class-locked).
  const float4* __restrict__ w4 =
      reinterpret_cast<const float4*>(weight + (size_t)n * N_NEUR);
  FOR64(WDECL)
  FOR64(WLOADPIN)

  const uint32_t idx = (uint32_t)(s * N_NEUR + n);

  float hist[20];
  if (t0 == 0) {
#pragma unroll
    for (int i = 0; i < 20; ++i) hist[i] = 0.0f;
  } else {
#pragma unroll
    for (int i = 0; i < 20; ++i) hist[i] = histws[i * LANES + idx];
  }

  const size_t plane = (size_t)N_SAMP * T_BINS * N_NEUR;
  float* __restrict__ out_spk = out + 0 * plane + (size_t)s * T_BINS * N_NEUR + n;
  float* __restrict__ out_cnv = out + 1 * plane + (size_t)s * T_BINS * N_NEUR + n;
  float* __restrict__ out_rte = out + 2 * plane + (size_t)s * T_BINS * N_NEUR + n;

  uint32_t skreg = 0;
  float4 sc0, sc1;
  if constexpr (MODE == 0) {
    if (n < 2 * J_MAX) skreg = sub[(size_t)t0 * (2 * J_MAX) + n];
  } else {
    const float4* p = reinterpret_cast<const float4*>(S8_in + (size_t)idx * J_PRE);
    sc0 = p[0]; sc1 = p[1];
  }

  __syncthreads();  // fb visible

  for (int t = t0; t < t1; ++t) {
    const int buf = t & 1;
    float* __restrict__ convbuf = convb[buf];
    const float4* __restrict__ convbuf4 = reinterpret_cast<const float4*>(convbuf);

    float4 sn0, sn1;
    if constexpr (MODE == 0) {
      uint32_t* __restrict__ skbuf = skb[buf];
      if (n < 2 * J_MAX) {
        skbuf[n] = skreg;
        const int tn = (t + 1 < t1) ? t + 1 : t;
        skreg = sub[(size_t)tn * (2 * J_MAX) + n];
      }
    } else {
      const int tn = (t + 1 < t1) ? t + 1 : t;
      const float4* p = reinterpret_cast<const float4*>(
          S8_in + ((size_t)(tn - t0) * LANES + idx) * J_PRE);
      sn0 = p[0]; sn1 = p[1];
    }

    // conv: ascending w, unfused mul+add (order bit-locked)
    float conv = 0.0f;
#pragma unroll
    for (int w = 0; w < 20; ++w) {
#if CONV_FMA
      conv = __builtin_fmaf(fb[w], hist[w], conv);
#else
      conv = fadd_s(conv, fmul_s(fb[w], hist[w]));
#endif
    }
    convbuf[n] = conv;

#if RAW_BARRIER
    asm volatile("s_waitcnt lgkmcnt(0)\n\ts_barrier" ::: "memory");
#else
    __syncthreads();
#endif

    // z = sum_k conv[k]*W[n][k], fused FMA ascending k (order bit-locked).
    // Ping-pong software pipeline: chunk c+1's cv loads issue before chunk
    // c's FMAs (read->use distance ~1 chunk), AGPR reads interleaved per quad.
    float zacc = 0.0f;
    {
      float4 cvA0, cvA1, cvA2, cvA3, cvA4, cvA5, cvA6, cvA7;
      float4 cvB0, cvB1, cvB2, cvB3, cvB4, cvB5, cvB6, cvB7;
      ZLOAD_A(0,1,2,3,4,5,6,7)
      ZLOAD_B(8,9,10,11,12,13,14,15)   ZCOMP_A(0,1,2,3,4,5,6,7)
      ZLOAD_A(16,17,18,19,20,21,22,23) ZCOMP_B(8,9,10,11,12,13,14,15)
      ZLOAD_B(24,25,26,27,28,29,30,31) ZCOMP_A(16,17,18,19,20,21,22,23)
      ZLOAD_A(32,33,34,35,36,37,38,39) ZCOMP_B(24,25,26,27,28,29,30,31)
      ZLOAD_B(40,41,42,43,44,45,46,47) ZCOMP_A(32,33,34,35,36,37,38,39)
      ZLOAD_A(48,49,50,51,52,53,54,55) ZCOMP_B(40,41,42,43,44,45,46,47)
      ZLOAD_B(56,57,58,59,60,61,62,63) ZCOMP_A(48,49,50,51,52,53,54,55)
      ZCOMP_B(56,57,58,59,60,61,62,63)
    }
    const float zb = fadd_s(zacc, bias_n);

    // lam = 1 / (1 + exp(-z))
    const float lam = 1.0f / fadd_s(1.0f, xla_expf(-zb));
    const float neg_lam = -lam;

    int r = 0;
    if constexpr (MODE == 1) {
      // S_j strictly non-increasing -> consecutive-count == count-all.
      r = (sc0.x > neg_lam) + (sc0.y > neg_lam) + (sc0.z > neg_lam) +
          (sc0.w > neg_lam) + (sc1.x > neg_lam) + (sc1.y > neg_lam) +
          (sc1.z > neg_lam) + (sc1.w > neg_lam);
      if (sc1.w > neg_lam) {  // rare (P <= 1e-5): continue the exact chain
        float S = sc1.w;
#pragma unroll 1
        for (int j = J_PRE; j < J_MAX; ++j) {
          const uint32_t k0 = sub[(size_t)t * (2 * J_MAX) + 2 * j];
          const uint32_t k1 = sub[(size_t)t * (2 * J_MAX) + 2 * j + 1];
          uint32_t o0, o1;
          threefry2x32(k0, k1, 0u, idx, o0, o1);
#if BITS32_XOR
          const uint32_t bits = o0 ^ o1;
#else
          const uint32_t bits = o1;
#endif
          const float u = __uint_as_float((bits >> 9) | 0x3f800000u) - 1.0f;
          S = fadd_s(S, xla_logf(u));
          if (S > neg_lam) ++r; else break;
        }
      }
    } else {
      uint32_t* __restrict__ skbuf = skb[buf];
      float S = 0.0f;
      bool done = false;
#pragma unroll 1
      for (int jb = 0; jb < J_MAX; jb += POISSON_BATCH) {
        float L[POISSON_BATCH];
#pragma unroll
        for (int q = 0; q < POISSON_BATCH; ++q) {
          const int j = jb + q;
          uint32_t o0, o1;
          threefry2x32(skbuf[2 * j], skbuf[2 * j + 1], 0u, idx, o0, o1);
#if BITS32_XOR
          const uint32_t bits = o0 ^ o1;
#else
          const uint32_t bits = o1;
#endif
          const float u = __uint_as_float((bits >> 9) | 0x3f800000u) - 1.0f;
          L[q] = xla_logf(u);
        }
#pragma unroll
        for (int q = 0; q < POISSON_BATCH; ++q) {
          if (!done) {
            S = fadd_s(S, L[q]);
            if (S > neg_lam) ++r; else done = true;
          }
        }
        if (__all(done)) break;
      }
    }
    const float spk = (float)r;

#pragma unroll
    for (int i = 0; i < 19; ++i) hist[i] = hist[i + 1];
    hist[19] = spk;

    const size_t off = (size_t)t * N_NEUR;
#if NT_STORES
    __builtin_nontemporal_store(spk,  out_spk + off);
    __builtin_nontemporal_store(conv, out_cnv + off);
    __builtin_nontemporal_store(lam,  out_rte + off);
#else
    out_spk[off] = spk;
    out_cnv[off] = conv;
    out_rte[off] = lam;
#endif
    if constexpr (MODE == 1) { sc0 = sn0; sc1 = sn1; }
#if !RAW_BARRIER
    __syncthreads();
#endif
  }

  // Chunk handoff: persist hist for the next launch.
  if (t1 < T_BINS) {
#pragma unroll
    for (int i = 0; i < 20; ++i) histws[i * LANES + idx] = hist[i];
  }
}

extern "C" void kernel_launch(void* const* d_in, const int* in_sizes, int n_in,
                              void* d_out, int out_size, void* d_ws, size_t ws_size,
                              hipStream_t stream) {
  const float* basis  = (const float*)d_in[0];
  const float* weight = (const float*)d_in[1];
  const float* bias   = (const float*)d_in[2];
  float* out = (float*)d_out;
  char* ws = (char*)d_ws;
  uint32_t* sub = (uint32_t*)ws;
  float* histws = (float*)(ws + HIST_OFF);

  hipLaunchKernelGGL(poglm_subkeys, dim3((T_BINS + 255) / 256), dim3(256), 0,
                     stream, sub);

  // Pick chunkT for DOUBLE-buffered S-table.
  int chunkT = 0;
  const int cand[4] = {256, 512, 128, 64};
  for (int ci = 0; ci < 4; ++ci) {
    const size_t bytes = (size_t)cand[ci] * LANES * J_PRE * 4;
    if (STBL_OFF + 2 * bytes <= ws_size) { chunkT = cand[ci]; break; }
  }

  if (chunkT == 0) {
    int sc = 0;
    for (int c = T_BINS; c >= 64; c >>= 1) {
      const size_t bytes = (size_t)c * LANES * J_PRE * 4;
      if (STBL_OFF + bytes <= ws_size) { sc = c; break; }
    }
    if (sc == 0) {
      hipLaunchKernelGGL((poglm_fused<0>), dim3(N_SAMP), dim3(256), 0,
                         stream, basis, weight, bias, sub, out,
                         (const float*)nullptr, (float*)nullptr, 0,
                         histws, 0, T_BINS);
      return;
    }
    float* stbl = (float*)(ws + STBL_OFF);
    for (int t0 = 0; t0 < T_BINS; t0 += sc) {
      hipLaunchKernelGGL(poglm_stable, dim3(sc * (LANES / 256)), dim3(256), 0,
                         stream, sub, stbl, t0);
      hipLaunchKernelGGL((poglm_fused<1>), dim3(N_SAMP), dim3(256), 0,
                         stream, basis, weight, bias, sub, out,
                         (const float*)stbl, (float*)nullptr, 0,
                         histws, t0, t0 + sc);
    }
    return;
  }

  const size_t stbl_bytes = (size_t)chunkT * LANES * J_PRE * 4;
  float* stbl0 = (float*)(ws + STBL_OFF);
  float* stbl1 = (float*)(ws + STBL_OFF + stbl_bytes);
  const int nstb = chunkT * (LANES / 256);
  const int nc = T_BINS / chunkT;

  hipLaunchKernelGGL(poglm_stable, dim3(nstb), dim3(256), 0, stream,
                     sub, stbl0, 0);

  for (int c = 0; c < nc; ++c) {
    const int t0 = c * chunkT, t1 = t0 + chunkT;
    float* cur = (c & 1) ? stbl1 : stbl0;
    float* nxt = (c & 1) ? stbl0 : stbl1;
    const bool more = (c + 1 < nc);
    hipLaunchKernelGGL((poglm_fused<1>),
                       dim3(N_SAMP + (more ? nstb : 0)), dim3(256), 0,
                       stream, basis, weight, bias, sub, out,
                       (const float*)cur, nxt, t1, histws, t0, t1);
  }
}

// Round 15
// 1866.750 us; speedup vs baseline: 1.6517x; 1.0430x over previous
//
#include <hip/hip_runtime.h>
#include <stdint.h>
#include <math.h>

// ============================================================================
// POGLM.sample — bit-exact replication of the JAX-CPU reference.
// R15: single-variable experiment on R14 — AGPR reads are NO LONGER volatile.
//      Volatile was only there to block LICM (R7); it also fenced the
//      scheduler (volatile asm cannot reorder), which R13/R14's invariant
//      ~4550cy/step suggests is the hidden cost. LICM is now blocked by a
//      dummy loop-variant operand "v"(t) instead: the read is a pure
//      function of (weight, t) -> not hoistable, but freely schedulable.
//      Arithmetic identical to passing R1-R14 (absmax 0.0625).
// Variant knobs:
#define THREEFRY_PARTITIONABLE 1
#define BITS32_XOR 1
#define VSL_FMA 0
#define CONV_FMA 0
#define RAW_BARRIER 1
#define POISSON_BATCH 4   // inline-path batch (MODE 0 fallback)
#define NT_STORES 1
#define J_PRE 8           // precomputed prefix depth
// ============================================================================

#define T_BINS 1024
#define N_SAMP 64
#define N_NEUR 256
#define J_MAX 32
#define LANES (N_SAMP * N_NEUR)  // 16384

// d_ws layout:
#define SUB_BYTES   (T_BINS * 2 * J_MAX * 4)
#define HIST_OFF    SUB_BYTES
#define HIST_BYTES  (20 * LANES * 4)
#define STBL_OFF    (HIST_OFF + HIST_BYTES)

// --- strict (non-contractable) f32 ops ---
static __device__ __forceinline__ float fmul_s(float a, float b) {
#pragma clang fp contract(off)
  return a * b;
}
static __device__ __forceinline__ float fadd_s(float a, float b) {
#pragma clang fp contract(off)
  return a + b;
}
static __device__ __forceinline__ float fsub_s(float a, float b) {
#pragma clang fp contract(off)
  return a - b;
}

#if VSL_FMA
#define MULADD(a, b, c) __builtin_fmaf((a), (b), (c))
#else
#define MULADD(a, b, c) fadd_s(fmul_s((a), (b)), (c))
#endif

// --- Threefry-2x32, 20 rounds (exact JAX semantics) ---
static __device__ __forceinline__ uint32_t rotl(uint32_t v, uint32_t d) {
  return (v << d) | (v >> (32u - d));
}
static __device__ __forceinline__ void threefry2x32(uint32_t k0, uint32_t k1,
                                                    uint32_t x0, uint32_t x1,
                                                    uint32_t& o0, uint32_t& o1) {
  const uint32_t k2 = k0 ^ k1 ^ 0x1BD11BDAu;
  x0 += k0; x1 += k1;
#define TF_RD(r) { x0 += x1; x1 = rotl(x1, r); x1 ^= x0; }
  TF_RD(13u) TF_RD(15u) TF_RD(26u) TF_RD(6u)
  x0 += k1; x1 += k2 + 1u;
  TF_RD(17u) TF_RD(29u) TF_RD(16u) TF_RD(24u)
  x0 += k2; x1 += k0 + 2u;
  TF_RD(13u) TF_RD(15u) TF_RD(26u) TF_RD(6u)
  x0 += k0; x1 += k1 + 3u;
  TF_RD(17u) TF_RD(29u) TF_RD(16u) TF_RD(24u)
  x0 += k1; x1 += k2 + 4u;
  TF_RD(13u) TF_RD(15u) TF_RD(26u) TF_RD(6u)
  x0 += k2; x1 += k0 + 5u;
#undef TF_RD
  o0 = x0; o1 = x1;
}

// --- XLA CPU Cephes expf (GenerateVF32Exp) ---
static __device__ __forceinline__ float xla_expf(float input) {
  float x = fminf(input, 88.3762626647950f);
  x = fmaxf(x, -88.3762626647949f);
  float fx = floorf(MULADD(x, 1.44269504088896341f, 0.5f));
  float tmp = fmul_s(0.693359375f, fx);
  float z = fmul_s(-2.12194440e-4f, fx);
  x = fsub_s(x, tmp);
  x = fsub_s(x, z);
  z = fmul_s(x, x);
  float y = MULADD(x, 1.9875691500e-4f, 1.3981999507e-3f);
  y = MULADD(y, x, 8.3334519073e-3f);
  y = MULADD(y, x, 4.1665795894e-2f);
  y = MULADD(y, x, 1.6666665459e-1f);
  y = MULADD(y, x, 5.0000001201e-1f);
  y = MULADD(y, z, x);
  y = fadd_s(1.0f, y);
  int n = (int)fx;
  float p2n = __int_as_float((uint32_t)(n + 127) << 23);
  float res = fmul_s(y, p2n);
  return fmaxf(res, input);
}

// --- XLA CPU Cephes logf (GenerateVF32Log); u in {0} U [2^-23, 1) here ---
static __device__ __forceinline__ float xla_logf(float u) {
  if (u == 0.0f) return -INFINITY;
  uint32_t b = __float_as_uint(u);
  float e = (float)((int)(b >> 23) - 127) + 1.0f;
  float m = __uint_as_float((b & 0x007fffffu) | 0x3f000000u);
  if (m < 0.707106781186547524f) {
    e = fsub_s(e, 1.0f);
    m = fadd_s(m, m);
  }
  m = fsub_s(m, 1.0f);
  float z = fmul_s(m, m);
  float y = MULADD(m, 7.0376836292e-2f, -1.1514610310e-1f);
  y = MULADD(y, m, 1.1676998740e-1f);
  y = MULADD(y, m, -1.2420140846e-1f);
  y = MULADD(y, m, 1.4249322787e-1f);
  y = MULADD(y, m, -1.6668057665e-1f);
  y = MULADD(y, m, 2.0000714765e-1f);
  y = MULADD(y, m, -2.4999993993e-1f);
  y = MULADD(y, m, 3.3333331174e-1f);
  y = fmul_s(y, m);
  y = fmul_s(y, z);
  y = MULADD(e, -2.12194440e-4f, y);
  y = MULADD(z, -0.5f, y);
  m = fadd_s(m, y);
  m = MULADD(e, 0.693359375f, m);
  return m;
}

// Shared S-prefix computation: 8 draws for (tt, ln), byte-identical chain.
static __device__ __forceinline__ void stable_body(
    const uint32_t* __restrict__ sub, float* __restrict__ dst8,
    int tt, int ln) {
  float S = 0.0f;
  float v[J_PRE];
#pragma unroll
  for (int j = 0; j < J_PRE; ++j) {
    const uint32_t k0 = sub[(size_t)tt * (2 * J_MAX) + 2 * j];
    const uint32_t k1 = sub[(size_t)tt * (2 * J_MAX) + 2 * j + 1];
    uint32_t o0, o1;
    threefry2x32(k0, k1, 0u, (uint32_t)ln, o0, o1);
#if BITS32_XOR
    const uint32_t bits = o0 ^ o1;
#else
    const uint32_t bits = o1;
#endif
    const float u = __uint_as_float((bits >> 9) | 0x3f800000u) - 1.0f;
    S = fadd_s(S, xla_logf(u));
    v[j] = S;
  }
  float4* dst = reinterpret_cast<float4*>(dst8);
  dst[0] = make_float4(v[0], v[1], v[2], v[3]);
  dst[1] = make_float4(v[4], v[5], v[6], v[7]);
}

// ============================================================================
// Kernel 1: per-time-step subkey chains. sub layout: [t][j][2] u32.
// ============================================================================
__global__ void poglm_subkeys(uint32_t* __restrict__ sub) {
  int t = blockIdx.x * blockDim.x + threadIdx.x;
  if (t >= T_BINS) return;
  uint32_t kt0, kt1;
#if THREEFRY_PARTITIONABLE
  threefry2x32(0u, 1u, 0u, (uint32_t)t, kt0, kt1);
#else
  {
    uint32_t i0 = 2u * t, i1 = 2u * t + 1u, a0, a1, b0, b1;
    if (i0 < 1024u) { threefry2x32(0u, 1u, i0, i0 + 1024u, a0, a1); kt0 = a0; }
    else            { threefry2x32(0u, 1u, i0 - 1024u, i0, a0, a1); kt0 = a1; }
    if (i1 < 1024u) { threefry2x32(0u, 1u, i1, i1 + 1024u, b0, b1); kt1 = b0; }
    else            { threefry2x32(0u, 1u, i1 - 1024u, i1, b0, b1); kt1 = b1; }
  }
#endif
  uint32_t r0 = kt0, r1 = kt1;
  for (int j = 0; j < J_MAX; ++j) {
    uint32_t s0, s1, n0, n1;
#if THREEFRY_PARTITIONABLE
    threefry2x32(r0, r1, 0u, 1u, s0, s1);
    threefry2x32(r0, r1, 0u, 0u, n0, n1);
#else
    uint32_t p00, p01, p10, p11;
    threefry2x32(r0, r1, 0u, 2u, p00, p01);
    threefry2x32(r0, r1, 1u, 3u, p10, p11);
    n0 = p00; n1 = p10;
    s0 = p01; s1 = p11;
#endif
    sub[(size_t)t * (2 * J_MAX) + 2 * j + 0] = s0;
    sub[(size_t)t * (2 * J_MAX) + 2 * j + 1] = s1;
    r0 = n0; r1 = n1;
  }
}

// ============================================================================
// Kernel 1b: standalone S-prefix table — used only for chunk 0.
// ============================================================================
__global__ __launch_bounds__(256)
void poglm_stable(const uint32_t* __restrict__ sub, float* __restrict__ S8,
                  int t0) {
  const int g  = blockIdx.x * 256 + threadIdx.x;
  const int tt = t0 + g / LANES;
  const int ln = g % LANES;
  stable_body(sub, S8 + (size_t)g * J_PRE, tt, ln);
}

// ---- 64 x float4 = 256 AGPR-resident weights --------------------------------
#define FOR64(M) \
  M(0) M(1) M(2) M(3) M(4) M(5) M(6) M(7) M(8) M(9) M(10) M(11) M(12) M(13) \
  M(14) M(15) M(16) M(17) M(18) M(19) M(20) M(21) M(22) M(23) M(24) M(25)   \
  M(26) M(27) M(28) M(29) M(30) M(31) M(32) M(33) M(34) M(35) M(36) M(37)   \
  M(38) M(39) M(40) M(41) M(42) M(43) M(44) M(45) M(46) M(47) M(48) M(49)   \
  M(50) M(51) M(52) M(53) M(54) M(55) M(56) M(57) M(58) M(59) M(60) M(61)   \
  M(62) M(63)

#define WDECL(i) float wA##i, wB##i, wC##i, wD##i;

#define WLOADPIN(i)                                                          \
  { const float4 v_ = w4[i];                                                 \
    asm volatile("v_accvgpr_write_b32 %0, %1" : "=a"(wA##i) : "v"(v_.x));    \
    asm volatile("v_accvgpr_write_b32 %0, %1" : "=a"(wB##i) : "v"(v_.y));    \
    asm volatile("v_accvgpr_write_b32 %0, %1" : "=a"(wC##i) : "v"(v_.z));    \
    asm volatile("v_accvgpr_write_b32 %0, %1" : "=a"(wD##i) : "v"(v_.w)); }

// NON-volatile AGPR read, LICM-blocked by dummy loop-variant operand %2
// (ignored by the template). Pure function of (weight, t): not hoistable,
// not cross-iteration CSE-able, but freely schedulable within the step.
#define AGET(dst, w)                                                         \
  asm("v_accvgpr_read_b32 %0, %1" : "=v"(dst) : "a"(w), "v"(t));

// Quad: 4 AGPR reads + 4 ascending-k fused FMAs (chain bit-locked by zacc
// dataflow; scheduler free to interleave).
#define QUAD(cvreg, i)                                                       \
  { float ta_, tb_, tc_, td_;                                                \
    AGET(ta_, wA##i) AGET(tb_, wB##i) AGET(tc_, wC##i) AGET(td_, wD##i)      \
    zacc = __builtin_fmaf(cvreg.x, ta_, zacc);                               \
    zacc = __builtin_fmaf(cvreg.y, tb_, zacc);                               \
    zacc = __builtin_fmaf(cvreg.z, tc_, zacc);                               \
    zacc = __builtin_fmaf(cvreg.w, td_, zacc); }

// Ping-pong cv sets: load chunk c+1's 8 float4 while computing chunk c.
#define ZLOAD_A(i0,i1,i2,i3,i4,i5,i6,i7)                                     \
  cvA0 = convbuf4[i0]; cvA1 = convbuf4[i1]; cvA2 = convbuf4[i2];             \
  cvA3 = convbuf4[i3]; cvA4 = convbuf4[i4]; cvA5 = convbuf4[i5];             \
  cvA6 = convbuf4[i6]; cvA7 = convbuf4[i7];
#define ZLOAD_B(i0,i1,i2,i3,i4,i5,i6,i7)                                     \
  cvB0 = convbuf4[i0]; cvB1 = convbuf4[i1]; cvB2 = convbuf4[i2];             \
  cvB3 = convbuf4[i3]; cvB4 = convbuf4[i4]; cvB5 = convbuf4[i5];             \
  cvB6 = convbuf4[i6]; cvB7 = convbuf4[i7];
#define ZCOMP_A(i0,i1,i2,i3,i4,i5,i6,i7)                                     \
  QUAD(cvA0,i0) QUAD(cvA1,i1) QUAD(cvA2,i2) QUAD(cvA3,i3)                    \
  QUAD(cvA4,i4) QUAD(cvA5,i5) QUAD(cvA6,i6) QUAD(cvA7,i7)
#define ZCOMP_B(i0,i1,i2,i3,i4,i5,i6,i7)                                     \
  QUAD(cvB0,i0) QUAD(cvB1,i1) QUAD(cvB2,i2) QUAD(cvB3,i3)                    \
  QUAD(cvB4,i4) QUAD(cvB5,i5) QUAD(cvB6,i6) QUAD(cvB7,i7)

// ============================================================================
// Kernel 2 (fused): blocks [0,64) = main simulation over [t0,t1) using S8_in;
// blocks [64, 64+nstb) = S-table for [tb0, tb0+chunkT) into S8_out.
// ============================================================================
template <int MODE>
__global__ __launch_bounds__(256, 1)
void poglm_fused(const float* __restrict__ basis, const float* __restrict__ weight,
                 const float* __restrict__ bias, const uint32_t* __restrict__ sub,
                 float* __restrict__ out, const float* __restrict__ S8_in,
                 float* __restrict__ S8_out, int tb0,
                 float* __restrict__ histws, int t0, int t1) {
  if (MODE == 1 && blockIdx.x >= N_SAMP) {
    const int g  = (blockIdx.x - N_SAMP) * 256 + threadIdx.x;
    const int tt = tb0 + g / LANES;
    const int ln = g % LANES;
    stable_body(sub, S8_out + (size_t)g * J_PRE, tt, ln);
    return;
  }

  __shared__ alignas(16) float convb[2][N_NEUR];
  __shared__ uint32_t skb[2][2 * J_MAX];
  __shared__ float fb[20];

  const int s = blockIdx.x;
  const int n = threadIdx.x;

  if (n < 20) fb[n] = basis[19 - n];
  const float bias_n = bias[n];

  // Whole weight row (256 scalars) resident in AGPRs.
  const float4* __restrict__ w4 =
      reinterpret_cast<const float4*>(weight + (size_t)n * N_NEUR);
  FOR64(WDECL)
  FOR64(WLOADPIN)

  const uint32_t idx = (uint32_t)(s * N_NEUR + n);

  float hist[20];
  if (t0 == 0) {
#pragma unroll
    for (int i = 0; i < 20; ++i) hist[i] = 0.0f;
  } else {
#pragma unroll
    for (int i = 0; i < 20; ++i) hist[i] = histws[i * LANES + idx];
  }

  const size_t plane = (size_t)N_SAMP * T_BINS * N_NEUR;
  float* __restrict__ out_spk = out + 0 * plane + (size_t)s * T_BINS * N_NEUR + n;
  float* __restrict__ out_cnv = out + 1 * plane + (size_t)s * T_BINS * N_NEUR + n;
  float* __restrict__ out_rte = out + 2 * plane + (size_t)s * T_BINS * N_NEUR + n;

  uint32_t skreg = 0;
  float4 sc0, sc1;
  if constexpr (MODE == 0) {
    if (n < 2 * J_MAX) skreg = sub[(size_t)t0 * (2 * J_MAX) + n];
  } else {
    const float4* p = reinterpret_cast<const float4*>(S8_in + (size_t)idx * J_PRE);
    sc0 = p[0]; sc1 = p[1];
  }

  __syncthreads();  // fb visible

  for (int t = t0; t < t1; ++t) {
    const int buf = t & 1;
    float* __restrict__ convbuf = convb[buf];
    const float4* __restrict__ convbuf4 = reinterpret_cast<const float4*>(convbuf);

    float4 sn0, sn1;
    if constexpr (MODE == 0) {
      uint32_t* __restrict__ skbuf = skb[buf];
      if (n < 2 * J_MAX) {
        skbuf[n] = skreg;
        const int tn = (t + 1 < t1) ? t + 1 : t;
        skreg = sub[(size_t)tn * (2 * J_MAX) + n];
      }
    } else {
      const int tn = (t + 1 < t1) ? t + 1 : t;
      const float4* p = reinterpret_cast<const float4*>(
          S8_in + ((size_t)(tn - t0) * LANES + idx) * J_PRE);
      sn0 = p[0]; sn1 = p[1];
    }

    // conv: ascending w, unfused mul+add (order bit-locked)
    float conv = 0.0f;
#pragma unroll
    for (int w = 0; w < 20; ++w) {
#if CONV_FMA
      conv = __builtin_fmaf(fb[w], hist[w], conv);
#else
      conv = fadd_s(conv, fmul_s(fb[w], hist[w]));
#endif
    }
    convbuf[n] = conv;

#if RAW_BARRIER
    asm volatile("s_waitcnt lgkmcnt(0)\n\ts_barrier" ::: "memory");
#else
    __syncthreads();
#endif

    // z = sum_k conv[k]*W[n][k], fused FMA ascending k (order bit-locked).
    float zacc = 0.0f;
    {
      float4 cvA0, cvA1, cvA2, cvA3, cvA4, cvA5, cvA6, cvA7;
      float4 cvB0, cvB1, cvB2, cvB3, cvB4, cvB5, cvB6, cvB7;
      ZLOAD_A(0,1,2,3,4,5,6,7)
      ZLOAD_B(8,9,10,11,12,13,14,15)   ZCOMP_A(0,1,2,3,4,5,6,7)
      ZLOAD_A(16,17,18,19,20,21,22,23) ZCOMP_B(8,9,10,11,12,13,14,15)
      ZLOAD_B(24,25,26,27,28,29,30,31) ZCOMP_A(16,17,18,19,20,21,22,23)
      ZLOAD_A(32,33,34,35,36,37,38,39) ZCOMP_B(24,25,26,27,28,29,30,31)
      ZLOAD_B(40,41,42,43,44,45,46,47) ZCOMP_A(32,33,34,35,36,37,38,39)
      ZLOAD_A(48,49,50,51,52,53,54,55) ZCOMP_B(40,41,42,43,44,45,46,47)
      ZLOAD_B(56,57,58,59,60,61,62,63) ZCOMP_A(48,49,50,51,52,53,54,55)
      ZCOMP_B(56,57,58,59,60,61,62,63)
    }
    const float zb = fadd_s(zacc, bias_n);

    // lam = 1 / (1 + exp(-z))
    const float lam = 1.0f / fadd_s(1.0f, xla_expf(-zb));
    const float neg_lam = -lam;

    int r = 0;
    if constexpr (MODE == 1) {
      // S_j strictly non-increasing -> consecutive-count == count-all.
      r = (sc0.x > neg_lam) + (sc0.y > neg_lam) + (sc0.z > neg_lam) +
          (sc0.w > neg_lam) + (sc1.x > neg_lam) + (sc1.y > neg_lam) +
          (sc1.z > neg_lam) + (sc1.w > neg_lam);
      if (sc1.w > neg_lam) {  // rare (P <= 1e-5): continue the exact chain
        float S = sc1.w;
#pragma unroll 1
        for (int j = J_PRE; j < J_MAX; ++j) {
          const uint32_t k0 = sub[(size_t)t * (2 * J_MAX) + 2 * j];
          const uint32_t k1 = sub[(size_t)t * (2 * J_MAX) + 2 * j + 1];
          uint32_t o0, o1;
          threefry2x32(k0, k1, 0u, idx, o0, o1);
#if BITS32_XOR
          const uint32_t bits = o0 ^ o1;
#else
          const uint32_t bits = o1;
#endif
          const float u = __uint_as_float((bits >> 9) | 0x3f800000u) - 1.0f;
          S = fadd_s(S, xla_logf(u));
          if (S > neg_lam) ++r; else break;
        }
      }
    } else {
      uint32_t* __restrict__ skbuf = skb[buf];
      float S = 0.0f;
      bool done = false;
#pragma unroll 1
      for (int jb = 0; jb < J_MAX; jb += POISSON_BATCH) {
        float L[POISSON_BATCH];
#pragma unroll
        for (int q = 0; q < POISSON_BATCH; ++q) {
          const int j = jb + q;
          uint32_t o0, o1;
          threefry2x32(skbuf[2 * j], skbuf[2 * j + 1], 0u, idx, o0, o1);
#if BITS32_XOR
          const uint32_t bits = o0 ^ o1;
#else
          const uint32_t bits = o1;
#endif
          const float u = __uint_as_float((bits >> 9) | 0x3f800000u) - 1.0f;
          L[q] = xla_logf(u);
        }
#pragma unroll
        for (int q = 0; q < POISSON_BATCH; ++q) {
          if (!done) {
            S = fadd_s(S, L[q]);
            if (S > neg_lam) ++r; else done = true;
          }
        }
        if (__all(done)) break;
      }
    }
    const float spk = (float)r;

#pragma unroll
    for (int i = 0; i < 19; ++i) hist[i] = hist[i + 1];
    hist[19] = spk;

    const size_t off = (size_t)t * N_NEUR;
#if NT_STORES
    __builtin_nontemporal_store(spk,  out_spk + off);
    __builtin_nontemporal_store(conv, out_cnv + off);
    __builtin_nontemporal_store(lam,  out_rte + off);
#else
    out_spk[off] = spk;
    out_cnv[off] = conv;
    out_rte[off] = lam;
#endif
    if constexpr (MODE == 1) { sc0 = sn0; sc1 = sn1; }
#if !RAW_BARRIER
    __syncthreads();
#endif
  }

  // Chunk handoff: persist hist for the next launch.
  if (t1 < T_BINS) {
#pragma unroll
    for (int i = 0; i < 20; ++i) histws[i * LANES + idx] = hist[i];
  }
}

extern "C" void kernel_launch(void* const* d_in, const int* in_sizes, int n_in,
                              void* d_out, int out_size, void* d_ws, size_t ws_size,
                              hipStream_t stream) {
  const float* basis  = (const float*)d_in[0];
  const float* weight = (const float*)d_in[1];
  const float* bias   = (const float*)d_in[2];
  float* out = (float*)d_out;
  char* ws = (char*)d_ws;
  uint32_t* sub = (uint32_t*)ws;
  float* histws = (float*)(ws + HIST_OFF);

  hipLaunchKernelGGL(poglm_subkeys, dim3((T_BINS + 255) / 256), dim3(256), 0,
                     stream, sub);

  // Pick chunkT for DOUBLE-buffered S-table.
  int chunkT = 0;
  const int cand[4] = {256, 512, 128, 64};
  for (int ci = 0; ci < 4; ++ci) {
    const size_t bytes = (size_t)cand[ci] * LANES * J_PRE * 4;
    if (STBL_OFF + 2 * bytes <= ws_size) { chunkT = cand[ci]; break; }
  }

  if (chunkT == 0) {
    int sc = 0;
    for (int c = T_BINS; c >= 64; c >>= 1) {
      const size_t bytes = (size_t)c * LANES * J_PRE * 4;
      if (STBL_OFF + bytes <= ws_size) { sc = c; break; }
    }
    if (sc == 0) {
      hipLaunchKernelGGL((poglm_fused<0>), dim3(N_SAMP), dim3(256), 0,
                         stream, basis, weight, bias, sub, out,
                         (const float*)nullptr, (float*)nullptr, 0,
                         histws, 0, T_BINS);
      return;
    }
    float* stbl = (float*)(ws + STBL_OFF);
    for (int t0 = 0; t0 < T_BINS; t0 += sc) {
      hipLaunchKernelGGL(poglm_stable, dim3(sc * (LANES / 256)), dim3(256), 0,
                         stream, sub, stbl, t0);
      hipLaunchKernelGGL((poglm_fused<1>), dim3(N_SAMP), dim3(256), 0,
                         stream, basis, weight, bias, sub, out,
                         (const float*)stbl, (float*)nullptr, 0,
                         histws, t0, t0 + sc);
    }
    return;
  }

  const size_t stbl_bytes = (size_t)chunkT * LANES * J_PRE * 4;
  float* stbl0 = (float*)(ws + STBL_OFF);
  float* stbl1 = (float*)(ws + STBL_OFF + stbl_bytes);
  const int nstb = chunkT * (LANES / 256);
  const int nc = T_BINS / chunkT;

  hipLaunchKernelGGL(poglm_stable, dim3(nstb), dim3(256), 0, stream,
                     sub, stbl0, 0);

  for (int c = 0; c < nc; ++c) {
    const int t0 = c * chunkT, t1 = t0 + chunkT;
    float* cur = (c & 1) ? stbl1 : stbl0;
    float* nxt = (c & 1) ? stbl0 : stbl1;
    const bool more = (c + 1 < nc);
    hipLaunchKernelGGL((poglm_fused<1>),
                       dim3(N_SAMP + (more ? nstb : 0)), dim3(256), 0,
                       stream, basis, weight, bias, sub, out,
                       (const float*)cur, nxt, t1, histws, t0, t1);
  }
}

// Round 16
// 1789.734 us; speedup vs baseline: 1.7228x; 1.0430x over previous
//
#include <hip/hip_runtime.h>
#include <stdint.h>
#include <math.h>

// ============================================================================
// POGLM.sample — bit-exact replication of the JAX-CPU reference.
// R16: (a) s_setprio(1) on main path (stable waves stay prio 0) — the fused
//      kernel gives each SIMD 1 main + 1 stable wave; priority keeps the
//      latency-critical main wave winning issue slots (T5 mechanism).
//      (b) conv software-pipelined: prefix cp (w=0..18, inputs ready at step
//      start) computed inside the z-phase (fills FMA bubbles); post-spk conv
//      is 2 ops. Chain composition identical (post-shift hist[w] ==
//      pre-shift hist[w+1]) -> bit-exact. fb hoisted to registers.
//      Arithmetic identical to passing R1-R15 (absmax 0.0625).
// Variant knobs:
#define THREEFRY_PARTITIONABLE 1
#define BITS32_XOR 1
#define VSL_FMA 0
#define CONV_FMA 0
#define RAW_BARRIER 1
#define POISSON_BATCH 4   // inline-path batch (MODE 0 fallback)
#define NT_STORES 1
#define J_PRE 8           // precomputed prefix depth
// ============================================================================

#define T_BINS 1024
#define N_SAMP 64
#define N_NEUR 256
#define J_MAX 32
#define LANES (N_SAMP * N_NEUR)  // 16384

// d_ws layout:
#define SUB_BYTES   (T_BINS * 2 * J_MAX * 4)
#define HIST_OFF    SUB_BYTES
#define HIST_BYTES  (20 * LANES * 4)
#define STBL_OFF    (HIST_OFF + HIST_BYTES)

// --- strict (non-contractable) f32 ops ---
static __device__ __forceinline__ float fmul_s(float a, float b) {
#pragma clang fp contract(off)
  return a * b;
}
static __device__ __forceinline__ float fadd_s(float a, float b) {
#pragma clang fp contract(off)
  return a + b;
}
static __device__ __forceinline__ float fsub_s(float a, float b) {
#pragma clang fp contract(off)
  return a - b;
}

#if VSL_FMA
#define MULADD(a, b, c) __builtin_fmaf((a), (b), (c))
#else
#define MULADD(a, b, c) fadd_s(fmul_s((a), (b)), (c))
#endif

// --- Threefry-2x32, 20 rounds (exact JAX semantics) ---
static __device__ __forceinline__ uint32_t rotl(uint32_t v, uint32_t d) {
  return (v << d) | (v >> (32u - d));
}
static __device__ __forceinline__ void threefry2x32(uint32_t k0, uint32_t k1,
                                                    uint32_t x0, uint32_t x1,
                                                    uint32_t& o0, uint32_t& o1) {
  const uint32_t k2 = k0 ^ k1 ^ 0x1BD11BDAu;
  x0 += k0; x1 += k1;
#define TF_RD(r) { x0 += x1; x1 = rotl(x1, r); x1 ^= x0; }
  TF_RD(13u) TF_RD(15u) TF_RD(26u) TF_RD(6u)
  x0 += k1; x1 += k2 + 1u;
  TF_RD(17u) TF_RD(29u) TF_RD(16u) TF_RD(24u)
  x0 += k2; x1 += k0 + 2u;
  TF_RD(13u) TF_RD(15u) TF_RD(26u) TF_RD(6u)
  x0 += k0; x1 += k1 + 3u;
  TF_RD(17u) TF_RD(29u) TF_RD(16u) TF_RD(24u)
  x0 += k1; x1 += k2 + 4u;
  TF_RD(13u) TF_RD(15u) TF_RD(26u) TF_RD(6u)
  x0 += k2; x1 += k0 + 5u;
#undef TF_RD
  o0 = x0; o1 = x1;
}

// --- XLA CPU Cephes expf (GenerateVF32Exp) ---
static __device__ __forceinline__ float xla_expf(float input) {
  float x = fminf(input, 88.3762626647950f);
  x = fmaxf(x, -88.3762626647949f);
  float fx = floorf(MULADD(x, 1.44269504088896341f, 0.5f));
  float tmp = fmul_s(0.693359375f, fx);
  float z = fmul_s(-2.12194440e-4f, fx);
  x = fsub_s(x, tmp);
  x = fsub_s(x, z);
  z = fmul_s(x, x);
  float y = MULADD(x, 1.9875691500e-4f, 1.3981999507e-3f);
  y = MULADD(y, x, 8.3334519073e-3f);
  y = MULADD(y, x, 4.1665795894e-2f);
  y = MULADD(y, x, 1.6666665459e-1f);
  y = MULADD(y, x, 5.0000001201e-1f);
  y = MULADD(y, z, x);
  y = fadd_s(1.0f, y);
  int n = (int)fx;
  float p2n = __int_as_float((uint32_t)(n + 127) << 23);
  float res = fmul_s(y, p2n);
  return fmaxf(res, input);
}

// --- XLA CPU Cephes logf (GenerateVF32Log); u in {0} U [2^-23, 1) here ---
static __device__ __forceinline__ float xla_logf(float u) {
  if (u == 0.0f) return -INFINITY;
  uint32_t b = __float_as_uint(u);
  float e = (float)((int)(b >> 23) - 127) + 1.0f;
  float m = __uint_as_float((b & 0x007fffffu) | 0x3f000000u);
  if (m < 0.707106781186547524f) {
    e = fsub_s(e, 1.0f);
    m = fadd_s(m, m);
  }
  m = fsub_s(m, 1.0f);
  float z = fmul_s(m, m);
  float y = MULADD(m, 7.0376836292e-2f, -1.1514610310e-1f);
  y = MULADD(y, m, 1.1676998740e-1f);
  y = MULADD(y, m, -1.2420140846e-1f);
  y = MULADD(y, m, 1.4249322787e-1f);
  y = MULADD(y, m, -1.6668057665e-1f);
  y = MULADD(y, m, 2.0000714765e-1f);
  y = MULADD(y, m, -2.4999993993e-1f);
  y = MULADD(y, m, 3.3333331174e-1f);
  y = fmul_s(y, m);
  y = fmul_s(y, z);
  y = MULADD(e, -2.12194440e-4f, y);
  y = MULADD(z, -0.5f, y);
  m = fadd_s(m, y);
  m = MULADD(e, 0.693359375f, m);
  return m;
}

// Shared S-prefix computation: 8 draws for (tt, ln), byte-identical chain.
static __device__ __forceinline__ void stable_body(
    const uint32_t* __restrict__ sub, float* __restrict__ dst8,
    int tt, int ln) {
  float S = 0.0f;
  float v[J_PRE];
#pragma unroll
  for (int j = 0; j < J_PRE; ++j) {
    const uint32_t k0 = sub[(size_t)tt * (2 * J_MAX) + 2 * j];
    const uint32_t k1 = sub[(size_t)tt * (2 * J_MAX) + 2 * j + 1];
    uint32_t o0, o1;
    threefry2x32(k0, k1, 0u, (uint32_t)ln, o0, o1);
#if BITS32_XOR
    const uint32_t bits = o0 ^ o1;
#else
    const uint32_t bits = o1;
#endif
    const float u = __uint_as_float((bits >> 9) | 0x3f800000u) - 1.0f;
    S = fadd_s(S, xla_logf(u));
    v[j] = S;
  }
  float4* dst = reinterpret_cast<float4*>(dst8);
  dst[0] = make_float4(v[0], v[1], v[2], v[3]);
  dst[1] = make_float4(v[4], v[5], v[6], v[7]);
}

// ============================================================================
// Kernel 1: per-time-step subkey chains. sub layout: [t][j][2] u32.
// ============================================================================
__global__ void poglm_subkeys(uint32_t* __restrict__ sub) {
  int t = blockIdx.x * blockDim.x + threadIdx.x;
  if (t >= T_BINS) return;
  uint32_t kt0, kt1;
#if THREEFRY_PARTITIONABLE
  threefry2x32(0u, 1u, 0u, (uint32_t)t, kt0, kt1);
#else
  {
    uint32_t i0 = 2u * t, i1 = 2u * t + 1u, a0, a1, b0, b1;
    if (i0 < 1024u) { threefry2x32(0u, 1u, i0, i0 + 1024u, a0, a1); kt0 = a0; }
    else            { threefry2x32(0u, 1u, i0 - 1024u, i0, a0, a1); kt0 = a1; }
    if (i1 < 1024u) { threefry2x32(0u, 1u, i1, i1 + 1024u, b0, b1); kt1 = b0; }
    else            { threefry2x32(0u, 1u, i1 - 1024u, i1, b0, b1); kt1 = b1; }
  }
#endif
  uint32_t r0 = kt0, r1 = kt1;
  for (int j = 0; j < J_MAX; ++j) {
    uint32_t s0, s1, n0, n1;
#if THREEFRY_PARTITIONABLE
    threefry2x32(r0, r1, 0u, 1u, s0, s1);
    threefry2x32(r0, r1, 0u, 0u, n0, n1);
#else
    uint32_t p00, p01, p10, p11;
    threefry2x32(r0, r1, 0u, 2u, p00, p01);
    threefry2x32(r0, r1, 1u, 3u, p10, p11);
    n0 = p00; n1 = p10;
    s0 = p01; s1 = p11;
#endif
    sub[(size_t)t * (2 * J_MAX) + 2 * j + 0] = s0;
    sub[(size_t)t * (2 * J_MAX) + 2 * j + 1] = s1;
    r0 = n0; r1 = n1;
  }
}

// ============================================================================
// Kernel 1b: standalone S-prefix table — used only for chunk 0.
// ============================================================================
__global__ __launch_bounds__(256)
void poglm_stable(const uint32_t* __restrict__ sub, float* __restrict__ S8,
                  int t0) {
  const int g  = blockIdx.x * 256 + threadIdx.x;
  const int tt = t0 + g / LANES;
  const int ln = g % LANES;
  stable_body(sub, S8 + (size_t)g * J_PRE, tt, ln);
}

// ---- 64 x float4 = 256 AGPR-resident weights --------------------------------
#define FOR64(M) \
  M(0) M(1) M(2) M(3) M(4) M(5) M(6) M(7) M(8) M(9) M(10) M(11) M(12) M(13) \
  M(14) M(15) M(16) M(17) M(18) M(19) M(20) M(21) M(22) M(23) M(24) M(25)   \
  M(26) M(27) M(28) M(29) M(30) M(31) M(32) M(33) M(34) M(35) M(36) M(37)   \
  M(38) M(39) M(40) M(41) M(42) M(43) M(44) M(45) M(46) M(47) M(48) M(49)   \
  M(50) M(51) M(52) M(53) M(54) M(55) M(56) M(57) M(58) M(59) M(60) M(61)   \
  M(62) M(63)

#define WDECL(i) float wA##i, wB##i, wC##i, wD##i;

#define WLOADPIN(i)                                                          \
  { const float4 v_ = w4[i];                                                 \
    asm volatile("v_accvgpr_write_b32 %0, %1" : "=a"(wA##i) : "v"(v_.x));    \
    asm volatile("v_accvgpr_write_b32 %0, %1" : "=a"(wB##i) : "v"(v_.y));    \
    asm volatile("v_accvgpr_write_b32 %0, %1" : "=a"(wC##i) : "v"(v_.z));    \
    asm volatile("v_accvgpr_write_b32 %0, %1" : "=a"(wD##i) : "v"(v_.w)); }

// NON-volatile AGPR read, LICM-blocked by dummy loop-variant operand.
#define AGET(dst, w)                                                         \
  asm("v_accvgpr_read_b32 %0, %1" : "=v"(dst) : "a"(w), "v"(t));

// Quad: 4 AGPR reads + 4 ascending-k fused FMAs (chain bit-locked by zacc).
#define QUAD(cvreg, i)                                                       \
  { float ta_, tb_, tc_, td_;                                                \
    AGET(ta_, wA##i) AGET(tb_, wB##i) AGET(tc_, wC##i) AGET(td_, wD##i)      \
    zacc = __builtin_fmaf(cvreg.x, ta_, zacc);                               \
    zacc = __builtin_fmaf(cvreg.y, tb_, zacc);                               \
    zacc = __builtin_fmaf(cvreg.z, tc_, zacc);                               \
    zacc = __builtin_fmaf(cvreg.w, td_, zacc); }

// Ping-pong cv sets: load chunk c+1's 8 float4 while computing chunk c.
#define ZLOAD_A(i0,i1,i2,i3,i4,i5,i6,i7)                                     \
  cvA0 = convbuf4[i0]; cvA1 = convbuf4[i1]; cvA2 = convbuf4[i2];             \
  cvA3 = convbuf4[i3]; cvA4 = convbuf4[i4]; cvA5 = convbuf4[i5];             \
  cvA6 = convbuf4[i6]; cvA7 = convbuf4[i7];
#define ZLOAD_B(i0,i1,i2,i3,i4,i5,i6,i7)                                     \
  cvB0 = convbuf4[i0]; cvB1 = convbuf4[i1]; cvB2 = convbuf4[i2];             \
  cvB3 = convbuf4[i3]; cvB4 = convbuf4[i4]; cvB5 = convbuf4[i5];             \
  cvB6 = convbuf4[i6]; cvB7 = convbuf4[i7];
#define ZCOMP_A(i0,i1,i2,i3,i4,i5,i6,i7)                                     \
  QUAD(cvA0,i0) QUAD(cvA1,i1) QUAD(cvA2,i2) QUAD(cvA3,i3)                    \
  QUAD(cvA4,i4) QUAD(cvA5,i5) QUAD(cvA6,i6) QUAD(cvA7,i7)
#define ZCOMP_B(i0,i1,i2,i3,i4,i5,i6,i7)                                     \
  QUAD(cvB0,i0) QUAD(cvB1,i1) QUAD(cvB2,i2) QUAD(cvB3,i3)                    \
  QUAD(cvB4,i4) QUAD(cvB5,i5) QUAD(cvB6,i6) QUAD(cvB7,i7)

// ============================================================================
// Kernel 2 (fused): blocks [0,64) = main simulation over [t0,t1) using S8_in;
// blocks [64, 64+nstb) = S-table for [tb0, tb0+chunkT) into S8_out.
// ============================================================================
template <int MODE>
__global__ __launch_bounds__(256, 1)
void poglm_fused(const float* __restrict__ basis, const float* __restrict__ weight,
                 const float* __restrict__ bias, const uint32_t* __restrict__ sub,
                 float* __restrict__ out, const float* __restrict__ S8_in,
                 float* __restrict__ S8_out, int tb0,
                 float* __restrict__ histws, int t0, int t1) {
  if (MODE == 1 && blockIdx.x >= N_SAMP) {
    // stable filler path: priority 0 (default) — yields issue slots to main.
    const int g  = (blockIdx.x - N_SAMP) * 256 + threadIdx.x;
    const int tt = tb0 + g / LANES;
    const int ln = g % LANES;
    stable_body(sub, S8_out + (size_t)g * J_PRE, tt, ln);
    return;
  }

  // Latency-critical main path: elevated wave priority for SIMD arbitration
  // against co-resident stable waves.
  __builtin_amdgcn_s_setprio(1);

  __shared__ alignas(16) float convb[2][N_NEUR];
  __shared__ uint32_t skb[2][2 * J_MAX];
  __shared__ float fb_lds[20];

  const int s = blockIdx.x;
  const int n = threadIdx.x;

  if (n < 20) fb_lds[n] = basis[19 - n];
  const float bias_n = bias[n];

  // Whole weight row (256 scalars) resident in AGPRs.
  const float4* __restrict__ w4 =
      reinterpret_cast<const float4*>(weight + (size_t)n * N_NEUR);
  FOR64(WDECL)
  FOR64(WLOADPIN)

  const uint32_t idx = (uint32_t)(s * N_NEUR + n);

  float hist[20];
  if (t0 == 0) {
#pragma unroll
    for (int i = 0; i < 20; ++i) hist[i] = 0.0f;
  } else {
#pragma unroll
    for (int i = 0; i < 20; ++i) hist[i] = histws[i * LANES + idx];
  }

  const size_t plane = (size_t)N_SAMP * T_BINS * N_NEUR;
  float* __restrict__ out_spk = out + 0 * plane + (size_t)s * T_BINS * N_NEUR + n;
  float* __restrict__ out_cnv = out + 1 * plane + (size_t)s * T_BINS * N_NEUR + n;
  float* __restrict__ out_rte = out + 2 * plane + (size_t)s * T_BINS * N_NEUR + n;

  uint32_t skreg = 0;
  float4 sc0, sc1;
  if constexpr (MODE == 0) {
    if (n < 2 * J_MAX) skreg = sub[(size_t)t0 * (2 * J_MAX) + n];
  } else {
    const float4* p = reinterpret_cast<const float4*>(S8_in + (size_t)idx * J_PRE);
    sc0 = p[0]; sc1 = p[1];
  }

  __syncthreads();  // fb_lds visible

  // fb in registers (static indices -> VGPRs; kills 20 LDS reads/step).
  float fbr[20];
#pragma unroll
  for (int w = 0; w < 20; ++w) fbr[w] = fb_lds[w];

  // conv for step t0: full ascending-w chain (bit-exact prologue).
  float conv = 0.0f;
#pragma unroll
  for (int w = 0; w < 20; ++w) {
#if CONV_FMA
    conv = __builtin_fmaf(fbr[w], hist[w], conv);
#else
    conv = fadd_s(conv, fmul_s(fbr[w], hist[w]));
#endif
  }

  for (int t = t0; t < t1; ++t) {
    const int buf = t & 1;
    float* __restrict__ convbuf = convb[buf];
    const float4* __restrict__ convbuf4 = reinterpret_cast<const float4*>(convbuf);

    const float conv_cur = conv;     // this step's conv (computed last step)
    convbuf[n] = conv_cur;

    float4 sn0, sn1;
    if constexpr (MODE == 0) {
      uint32_t* __restrict__ skbuf = skb[buf];
      if (n < 2 * J_MAX) {
        skbuf[n] = skreg;
        const int tn = (t + 1 < t1) ? t + 1 : t;
        skreg = sub[(size_t)tn * (2 * J_MAX) + n];
      }
    } else {
      const int tn = (t + 1 < t1) ? t + 1 : t;
      const float4* p = reinterpret_cast<const float4*>(
          S8_in + ((size_t)(tn - t0) * LANES + idx) * J_PRE);
      sn0 = p[0]; sn1 = p[1];
    }

#if RAW_BARRIER
    asm volatile("s_waitcnt lgkmcnt(0)\n\ts_barrier" ::: "memory");
#else
    __syncthreads();
#endif

    // Next step's conv prefix (w=0..18 over hist[1..19], all known now).
    // Independent of z -> scheduler fills z's FMA bubbles with it.
    float cp = 0.0f;
#pragma unroll
    for (int w = 0; w < 19; ++w) {
#if CONV_FMA
      cp = __builtin_fmaf(fbr[w], hist[w + 1], cp);
#else
      cp = fadd_s(cp, fmul_s(fbr[w], hist[w + 1]));
#endif
    }

    // z = sum_k conv[k]*W[n][k], fused FMA ascending k (order bit-locked).
    float zacc = 0.0f;
    {
      float4 cvA0, cvA1, cvA2, cvA3, cvA4, cvA5, cvA6, cvA7;
      float4 cvB0, cvB1, cvB2, cvB3, cvB4, cvB5, cvB6, cvB7;
      ZLOAD_A(0,1,2,3,4,5,6,7)
      ZLOAD_B(8,9,10,11,12,13,14,15)   ZCOMP_A(0,1,2,3,4,5,6,7)
      ZLOAD_A(16,17,18,19,20,21,22,23) ZCOMP_B(8,9,10,11,12,13,14,15)
      ZLOAD_B(24,25,26,27,28,29,30,31) ZCOMP_A(16,17,18,19,20,21,22,23)
      ZLOAD_A(32,33,34,35,36,37,38,39) ZCOMP_B(24,25,26,27,28,29,30,31)
      ZLOAD_B(40,41,42,43,44,45,46,47) ZCOMP_A(32,33,34,35,36,37,38,39)
      ZLOAD_A(48,49,50,51,52,53,54,55) ZCOMP_B(40,41,42,43,44,45,46,47)
      ZLOAD_B(56,57,58,59,60,61,62,63) ZCOMP_A(48,49,50,51,52,53,54,55)
      ZCOMP_B(56,57,58,59,60,61,62,63)
    }
    const float zb = fadd_s(zacc, bias_n);

    // lam = 1 / (1 + exp(-z))
    const float lam = 1.0f / fadd_s(1.0f, xla_expf(-zb));
    const float neg_lam = -lam;

    int r = 0;
    if constexpr (MODE == 1) {
      // S_j strictly non-increasing -> consecutive-count == count-all.
      r = (sc0.x > neg_lam) + (sc0.y > neg_lam) + (sc0.z > neg_lam) +
          (sc0.w > neg_lam) + (sc1.x > neg_lam) + (sc1.y > neg_lam) +
          (sc1.z > neg_lam) + (sc1.w > neg_lam);
      if (__builtin_expect(sc1.w > neg_lam, 0)) {  // rare: continue chain
        float S = sc1.w;
#pragma unroll 1
        for (int j = J_PRE; j < J_MAX; ++j) {
          const uint32_t k0 = sub[(size_t)t * (2 * J_MAX) + 2 * j];
          const uint32_t k1 = sub[(size_t)t * (2 * J_MAX) + 2 * j + 1];
          uint32_t o0, o1;
          threefry2x32(k0, k1, 0u, idx, o0, o1);
#if BITS32_XOR
          const uint32_t bits = o0 ^ o1;
#else
          const uint32_t bits = o1;
#endif
          const float u = __uint_as_float((bits >> 9) | 0x3f800000u) - 1.0f;
          S = fadd_s(S, xla_logf(u));
          if (S > neg_lam) ++r; else break;
        }
      }
    } else {
      uint32_t* __restrict__ skbuf = skb[buf];
      float S = 0.0f;
      bool done = false;
#pragma unroll 1
      for (int jb = 0; jb < J_MAX; jb += POISSON_BATCH) {
        float L[POISSON_BATCH];
#pragma unroll
        for (int q = 0; q < POISSON_BATCH; ++q) {
          const int j = jb + q;
          uint32_t o0, o1;
          threefry2x32(skbuf[2 * j], skbuf[2 * j + 1], 0u, idx, o0, o1);
#if BITS32_XOR
          const uint32_t bits = o0 ^ o1;
#else
          const uint32_t bits = o1;
#endif
          const float u = __uint_as_float((bits >> 9) | 0x3f800000u) - 1.0f;
          L[q] = xla_logf(u);
        }
#pragma unroll
        for (int q = 0; q < POISSON_BATCH; ++q) {
          if (!done) {
            S = fadd_s(S, L[q]);
            if (S > neg_lam) ++r; else done = true;
          }
        }
        if (__all(done)) break;
      }
    }
    const float spk = (float)r;

#pragma unroll
    for (int i = 0; i < 19; ++i) hist[i] = hist[i + 1];
    hist[19] = spk;

    // Next step's conv: prefix + last term (bit-identical composition).
    conv = fadd_s(cp, fmul_s(fbr[19], spk));

    const size_t off = (size_t)t * N_NEUR;
#if NT_STORES
    __builtin_nontemporal_store(spk,      out_spk + off);
    __builtin_nontemporal_store(conv_cur, out_cnv + off);
    __builtin_nontemporal_store(lam,      out_rte + off);
#else
    out_spk[off] = spk;
    out_cnv[off] = conv_cur;
    out_rte[off] = lam;
#endif
    if constexpr (MODE == 1) { sc0 = sn0; sc1 = sn1; }
#if !RAW_BARRIER
    __syncthreads();
#endif
  }

  // Chunk handoff: persist hist for the next launch.
  if (t1 < T_BINS) {
#pragma unroll
    for (int i = 0; i < 20; ++i) histws[i * LANES + idx] = hist[i];
  }
}

extern "C" void kernel_launch(void* const* d_in, const int* in_sizes, int n_in,
                              void* d_out, int out_size, void* d_ws, size_t ws_size,
                              hipStream_t stream) {
  const float* basis  = (const float*)d_in[0];
  const float* weight = (const float*)d_in[1];
  const float* bias   = (const float*)d_in[2];
  float* out = (float*)d_out;
  char* ws = (char*)d_ws;
  uint32_t* sub = (uint32_t*)ws;
  float* histws = (float*)(ws + HIST_OFF);

  hipLaunchKernelGGL(poglm_subkeys, dim3((T_BINS + 255) / 256), dim3(256), 0,
                     stream, sub);

  // Pick chunkT for DOUBLE-buffered S-table.
  int chunkT = 0;
  const int cand[4] = {256, 512, 128, 64};
  for (int ci = 0; ci < 4; ++ci) {
    const size_t bytes = (size_t)cand[ci] * LANES * J_PRE * 4;
    if (STBL_OFF + 2 * bytes <= ws_size) { chunkT = cand[ci]; break; }
  }

  if (chunkT == 0) {
    int sc = 0;
    for (int c = T_BINS; c >= 64; c >>= 1) {
      const size_t bytes = (size_t)c * LANES * J_PRE * 4;
      if (STBL_OFF + bytes <= ws_size) { sc = c; break; }
    }
    if (sc == 0) {
      hipLaunchKernelGGL((poglm_fused<0>), dim3(N_SAMP), dim3(256), 0,
                         stream, basis, weight, bias, sub, out,
                         (const float*)nullptr, (float*)nullptr, 0,
                         histws, 0, T_BINS);
      return;
    }
    float* stbl = (float*)(ws + STBL_OFF);
    for (int t0 = 0; t0 < T_BINS; t0 += sc) {
      hipLaunchKernelGGL(poglm_stable, dim3(sc * (LANES / 256)), dim3(256), 0,
                         stream, sub, stbl, t0);
      hipLaunchKernelGGL((poglm_fused<1>), dim3(N_SAMP), dim3(256), 0,
                         stream, basis, weight, bias, sub, out,
                         (const float*)stbl, (float*)nullptr, 0,
                         histws, t0, t0 + sc);
    }
    return;
  }

  const size_t stbl_bytes = (size_t)chunkT * LANES * J_PRE * 4;
  float* stbl0 = (float*)(ws + STBL_OFF);
  float* stbl1 = (float*)(ws + STBL_OFF + stbl_bytes);
  const int nstb = chunkT * (LANES / 256);
  const int nc = T_BINS / chunkT;

  hipLaunchKernelGGL(poglm_stable, dim3(nstb), dim3(256), 0, stream,
                     sub, stbl0, 0);

  for (int c = 0; c < nc; ++c) {
    const int t0 = c * chunkT, t1 = t0 + chunkT;
    float* cur = (c & 1) ? stbl1 : stbl0;
    float* nxt = (c & 1) ? stbl0 : stbl1;
    const bool more = (c + 1 < nc);
    hipLaunchKernelGGL((poglm_fused<1>),
                       dim3(N_SAMP + (more ? nstb : 0)), dim3(256), 0,
                       stream, basis, weight, bias, sub, out,
                       (const float*)cur, nxt, t1, histws, t0, t1);
  }
}